// Round 4
// baseline (908.744 us; speedup 1.0000x reference)
//
#include <hip/hip_runtime.h>

static constexpr int NB = 128;
static constexpr int NT = 256;
static constexpr int NV = 64;
static constexpr int NBT = NB * NT;       // 32768
static constexpr int NBTV = NBT * NV;     // 2097152

typedef __attribute__((ext_vector_type(8))) short short8;
typedef __attribute__((ext_vector_type(4))) float f32x4;

__device__ __forceinline__ unsigned short f2bf(float x) {
    unsigned int u = __float_as_uint(x);
    return (unsigned short)((u + 0x7FFFu + ((u >> 16) & 1u)) >> 16);
}
__device__ __forceinline__ float bf2f(unsigned short b) {
    return __uint_as_float(((unsigned int)b) << 16);
}
__device__ __forceinline__ float sigm(float x) { return 1.0f / (1.0f + expf(-x)); }
// fast device transcendentals (v_exp + v_rcp)
__device__ __forceinline__ float fsigm(float x) {
    return __builtin_amdgcn_rcpf(1.0f + __expf(-x));
}
__device__ __forceinline__ float ftanh(float x) {
    return 1.0f - 2.0f * __builtin_amdgcn_rcpf(1.0f + __expf(2.0f * x));
}

__device__ __forceinline__ short8 pack8(float4 a, float4 b) {
    short8 r;
    r[0] = (short)f2bf(a.x); r[1] = (short)f2bf(a.y); r[2] = (short)f2bf(a.z); r[3] = (short)f2bf(a.w);
    r[4] = (short)f2bf(b.x); r[5] = (short)f2bf(b.y); r[6] = (short)f2bf(b.z); r[7] = (short)f2bf(b.w);
    return r;
}

__device__ __forceinline__ void dot4(float4& acc, const float4 wv, const float4 xv) {
    acc.x = fmaf(wv.x, xv.x, acc.x);
    acc.y = fmaf(wv.y, xv.y, acc.y);
    acc.z = fmaf(wv.z, xv.z, acc.z);
    acc.w = fmaf(wv.w, xv.w, acc.w);
}

// ---------------- K0: weight conversions to bf16 ----------------
__global__ void k_conv(const float* __restrict__ Wf, const float* __restrict__ Wihf,
                       const float* __restrict__ Wihb, const float* __restrict__ Wihg,
                       const float* __restrict__ Whhf, const float* __restrict__ Whhb,
                       const float* __restrict__ Whhg,
                       unsigned short* __restrict__ wbf, float* __restrict__ wdiag,
                       unsigned short* __restrict__ wgf, unsigned short* __restrict__ wgb,
                       unsigned short* __restrict__ wgg,
                       unsigned short* __restrict__ whhf_bf, unsigned short* __restrict__ whhb_bf,
                       unsigned short* __restrict__ whhg_bf) {
    int i = blockIdx.x * 256 + threadIdx.x;
    if (i < NV * 32 * NV) wbf[i] = f2bf(Wf[i]);
    if (i < 2048) wdiag[i] = bf2f(f2bf(Wf[i * 64 + (i >> 5)]));
    if (i < 32768) {
        int n = i >> 7, k = i & 127;
        wgf[i] = f2bf(Wihf[n * 192 + k]);
        wgb[i] = f2bf(Wihb[n * 192 + k]);
    }
    if (i < 12288) wgg[i] = f2bf(Wihg[i]);
    if (i < 16384) { whhf_bf[i] = f2bf(Whhf[i]); whhb_bf[i] = f2bf(Whhb[i]); }
    if (i < 3072) whhg_bf[i] = f2bf(Whhg[i]);
}

// ---------------- K1: per-(b,v) stats ----------------
__global__ void k_stats(const int* __restrict__ lengths, const float* __restrict__ values,
                        const float* __restrict__ masks, const float* __restrict__ minv,
                        const float* __restrict__ maxv, float* __restrict__ stats,
                        float* __restrict__ mmn_ws, float* __restrict__ nmeans_ws) {
    int b = blockIdx.x; int v = threadIdx.x;
    const float* vp = values + (size_t)b * NT * NV + v;
    const float* mp = masks + (size_t)b * NT * NV + v;
    float sv = 0.f, sq = 0.f, sm = 0.f;
    for (int t = 0; t < NT; t++) {
        float x = vp[t * NV]; float m = mp[t * NV];
        sv += x; sq += x * x; sm += m;
    }
    float mean = sv / sm;
    float var = (sq - 2.0f * mean * sv + (float)NT * mean * mean) / (sm - 1.0f);
    var = fmaxf(var, 0.0f);
    float sd = sqrtf(var);
    float lf = (float)lengths[b];
    float miss = 1.0f - sm / lf;
    float mn = minv[b * NV + v]; float mx = maxv[b * NV + v];
    float mm = fmaxf(mx - mn, 1e-8f);
    float* st = stats + b * 256;
    if (v == 0) st[0] = lf;
    st[1 + v] = mean; st[65 + v] = sd; st[129 + v] = miss;
    mmn_ws[b * NV + v] = mm;
    nmeans_ws[b * NV + v] = (mean - mn) / mm;
}

// ---------------- K2: forward-fill + decay + x_complete + gamma ----------------
__global__ void k_fill(const float* __restrict__ values, const float* __restrict__ masks,
                       const float* __restrict__ deltas, const float* __restrict__ minv,
                       const float* __restrict__ Wd, const float* __restrict__ bd,
                       const float* __restrict__ mmn_ws, const float* __restrict__ nmeans_ws,
                       float* __restrict__ xcomp, float* __restrict__ gam) {
    int b = blockIdx.x; int v = threadIdx.x;
    size_t base = (size_t)b * NT * NV + v;
    float mn = minv[b * NV + v];
    float mm = mmn_ws[b * NV + v];
    float nmean = nmeans_ws[b * NV + v];
    float wd = Wd[v * NV + v], bdv = bd[v];
    float xp = 0.f, nvprev = 0.f, mprev = 0.f;
    for (int t = 0; t < NT; t++) {
        size_t i = base + (size_t)t * NV;
        float val = values[i], m = masks[i], d = deltas[i];
        float nv = (val - mn) / mm;
        if (t == 0) xp = nv; else xp = mprev * nvprev + (1.0f - mprev) * xp;
        float g = expf(-fmaxf(fmaf(d, wd, bdv), 0.0f));
        float xd = g * xp + (1.0f - g) * nmean;
        float xc = m * nv + (1.0f - m) * xd;
        xcomp[i] = xc; gam[i] = g;
        mprev = m; nvprev = nv;
    }
}

// ---------------- K_gates: MFMA GEMM, A rows = 16 samples at fixed t ----------------
// outputs in blocked-transposed layout [bgrp][t][n][16 s]
__global__ __launch_bounds__(256) void k_gates(
    const float* __restrict__ xcomp, const float* __restrict__ masks,
    const unsigned short* __restrict__ wgf, const unsigned short* __restrict__ wgb,
    const unsigned short* __restrict__ wgg, const float* __restrict__ bihg,
    float* __restrict__ gf, float* __restrict__ gb, float* __restrict__ gg) {
    int wave = threadIdx.x >> 6, lane = threadIdx.x & 63;
    int wg = blockIdx.x * 4 + wave;
    int t = wg >> 3, bgrp = wg & 7, b0 = bgrp * 16;
    int r = lane & 15, kc = lane >> 4;
    const float* xr = xcomp + ((size_t)(b0 + r) * NT + t) * NV + kc * 8;
    const float* mr = masks + ((size_t)(b0 + r) * NT + t) * NV + kc * 8;
    short8 af0 = pack8(*(const float4*)(xr), *(const float4*)(xr + 4));
    short8 af1 = pack8(*(const float4*)(xr + 32), *(const float4*)(xr + 36));
    short8 af2 = pack8(*(const float4*)(mr), *(const float4*)(mr + 4));
    short8 af3 = pack8(*(const float4*)(mr + 32), *(const float4*)(mr + 36));
    size_t obL = ((size_t)bgrp * NT + t) * 256;
    #pragma unroll 4
    for (int nt = 0; nt < 16; nt++) {
        const unsigned short* w = wgf + (size_t)(nt * 16 + r) * 128 + kc * 8;
        f32x4 acc = {0.f, 0.f, 0.f, 0.f};
        acc = __builtin_amdgcn_mfma_f32_16x16x32_bf16(af0, *(const short8*)(w), acc, 0, 0, 0);
        acc = __builtin_amdgcn_mfma_f32_16x16x32_bf16(af1, *(const short8*)(w + 32), acc, 0, 0, 0);
        acc = __builtin_amdgcn_mfma_f32_16x16x32_bf16(af2, *(const short8*)(w + 64), acc, 0, 0, 0);
        acc = __builtin_amdgcn_mfma_f32_16x16x32_bf16(af3, *(const short8*)(w + 96), acc, 0, 0, 0);
        *(f32x4*)(gf + (obL + nt * 16 + r) * 16 + kc * 4) = acc;
    }
    #pragma unroll 4
    for (int nt = 0; nt < 16; nt++) {
        const unsigned short* w = wgb + (size_t)(nt * 16 + r) * 128 + kc * 8;
        f32x4 acc = {0.f, 0.f, 0.f, 0.f};
        acc = __builtin_amdgcn_mfma_f32_16x16x32_bf16(af0, *(const short8*)(w), acc, 0, 0, 0);
        acc = __builtin_amdgcn_mfma_f32_16x16x32_bf16(af1, *(const short8*)(w + 32), acc, 0, 0, 0);
        acc = __builtin_amdgcn_mfma_f32_16x16x32_bf16(af2, *(const short8*)(w + 64), acc, 0, 0, 0);
        acc = __builtin_amdgcn_mfma_f32_16x16x32_bf16(af3, *(const short8*)(w + 96), acc, 0, 0, 0);
        *(f32x4*)(gb + (obL + nt * 16 + r) * 16 + kc * 4) = acc;
    }
    size_t obG = ((size_t)bgrp * NT + t) * 96;
    #pragma unroll 3
    for (int nt = 0; nt < 6; nt++) {
        const unsigned short* w = wgg + (size_t)(nt * 16 + r) * 128 + kc * 8;
        float bias = bihg[nt * 16 + r];
        f32x4 acc = {bias, bias, bias, bias};
        acc = __builtin_amdgcn_mfma_f32_16x16x32_bf16(af0, *(const short8*)(w), acc, 0, 0, 0);
        acc = __builtin_amdgcn_mfma_f32_16x16x32_bf16(af1, *(const short8*)(w + 32), acc, 0, 0, 0);
        acc = __builtin_amdgcn_mfma_f32_16x16x32_bf16(af2, *(const short8*)(w + 64), acc, 0, 0, 0);
        acc = __builtin_amdgcn_mfma_f32_16x16x32_bf16(af3, *(const short8*)(w + 96), acc, 0, 0, 0);
        *(f32x4*)(gg + (obG + nt * 16 + r) * 16 + kc * 4) = acc;
    }
}

// ---------------- K3: ctx MLP ----------------
__global__ void k_ctxmlp(const float* __restrict__ stats, const float* __restrict__ Wc1,
                         const float* __restrict__ bc1, const float* __restrict__ Wc2,
                         const float* __restrict__ bc2, float* __restrict__ ctx) {
    int b = blockIdx.x, tid = threadIdx.x;  // 64 threads
    __shared__ float lw[64 * 193];
    __shared__ float ss[193];
    __shared__ float h1[64];
    for (int i = tid; i < 64 * 193; i += 64) lw[i] = Wc1[i];
    ss[tid] = stats[b * 256 + tid];
    ss[64 + tid] = stats[b * 256 + 64 + tid];
    ss[128 + tid] = stats[b * 256 + 128 + tid];
    if (tid == 0) ss[192] = stats[b * 256 + 192];
    __syncthreads();
    float acc = bc1[tid];
    const float* w = lw + tid * 193;
    for (int k = 0; k < 193; k++) acc = fmaf(w[k], ss[k], acc);
    h1[tid] = fmaxf(acc, 0.f);
    __syncthreads();
    if (tid < 32) {
        float a = bc2[tid];
        const float* w2 = Wc2 + tid * 64;
        for (int k = 0; k < 64; k++) a = fmaf(w2[k], h1[k], a);
        ctx[b * 64 + tid] = a;
    }
}

// ---------------- K4: GRU, MFMA over 16 samples ----------------
__global__ __launch_bounds__(256, 1) void k_gru(
    const float* __restrict__ gg_t, const int* __restrict__ lengths,
    const unsigned short* __restrict__ whhg_bf, const float* __restrict__ bhh,
    float* __restrict__ ctx) {
    int bgrp = blockIdx.x; int b0 = bgrp * 16;
    int tid = threadIdx.x; int wave = tid >> 6; int lane = tid & 63;
    int r = lane & 15, kc = lane >> 4;
    __shared__ float h_lds[32][17];
    __shared__ float g_lds[16][100];

    short8 wbg[2];
    float bh[2] = {0.f, 0.f};
    if (wave < 3) {
        #pragma unroll
        for (int tt = 0; tt < 2; tt++) {
            int n = wave * 32 + tt * 16 + r;
            wbg[tt] = *(const short8*)(whhg_bf + (size_t)n * 32 + kc * 8);
            bh[tt] = bhh[n];
        }
    }
    int us = tid >> 4;
    int uv = (tid & 15) * 2;
    float hprev[2] = {0.f, 0.f};
    float hn[2] = {0.f, 0.f};
    int len = lengths[b0 + us];
    h_lds[uv][us] = 0.f; h_lds[uv + 1][us] = 0.f;
    const float* gbase = gg_t + (size_t)bgrp * NT * 96 * 16;
    __syncthreads();

    for (int t = 0; t < NT; t++) {
        float gi[6];
        const float* gt = gbase + (size_t)t * 96 * 16;
        #pragma unroll
        for (int g = 0; g < 3; g++) {
            gi[g * 2 + 0] = gt[(g * 32 + uv + 0) * 16 + us];
            gi[g * 2 + 1] = gt[(g * 32 + uv + 1) * 16 + us];
        }
        if (wave < 3) {
            short8 a;
            #pragma unroll
            for (int j = 0; j < 8; j++)
                a[j] = (short)(__float_as_uint(h_lds[kc * 8 + j][r]) >> 16);
            #pragma unroll
            for (int tt = 0; tt < 2; tt++) {
                f32x4 acc = {bh[tt], bh[tt], bh[tt], bh[tt]};
                acc = __builtin_amdgcn_mfma_f32_16x16x32_bf16(a, wbg[tt], acc, 0, 0, 0);
                int n = wave * 32 + tt * 16 + r;
                #pragma unroll
                for (int i = 0; i < 4; i++) g_lds[kc * 4 + i][n] = acc[i];
            }
        }
        __syncthreads();
        #pragma unroll
        for (int j = 0; j < 2; j++) {
            float hr = g_lds[us][uv + j];
            float hz = g_lds[us][32 + uv + j];
            float hnn = g_lds[us][64 + uv + j];
            float rr = fsigm(gi[j] + hr);
            float zz = fsigm(gi[2 + j] + hz);
            float nn = ftanh(gi[4 + j] + rr * hnn);
            float h = (1.f - zz) * nn + zz * hprev[j];
            hprev[j] = h;
            if (t < len) hn[j] = h;
        }
        h_lds[uv][us] = hprev[0];
        h_lds[uv + 1][us] = hprev[1];
        __syncthreads();
    }
    ctx[(b0 + us) * 64 + 32 + uv] = hn[0];
    ctx[(b0 + us) * 64 + 32 + uv + 1] = hn[1];
}

// ---------------- K5: hinit ----------------
__global__ void k_hinit(const float* __restrict__ ctx, const float* __restrict__ Wi,
                        const float* __restrict__ bi, float* __restrict__ hinit) {
    int b = blockIdx.x; int j = threadIdx.x;  // 128
    __shared__ __align__(16) float sc[64];
    if (j < 64) sc[j] = ctx[b * 64 + j];
    __syncthreads();
    const float4* w = (const float4*)(Wi + (size_t)j * 64);
    const float4* c4 = (const float4*)sc;
    float4 a = {0, 0, 0, 0};
    #pragma unroll
    for (int q = 0; q < 16; q++) dot4(a, w[q], c4[q]);
    hinit[b * 128 + j] = bi[j] + a.x + a.y + a.z + a.w;
}

// ---------------- K_cterm: ctx-part of LSTM gates + biases, layout [dir*8+bgrp][n][s] ----------------
__global__ void k_cterm(const float* __restrict__ ctx,
                        const float* __restrict__ Wihf, const float* __restrict__ Wihb,
                        const float* __restrict__ bihf, const float* __restrict__ bhhf,
                        const float* __restrict__ bihb, const float* __restrict__ bhhb,
                        float* __restrict__ ct_out) {
    int bx = blockIdx.x; int dir = bx >> 3; int bgrp = bx & 7; int b0 = bgrp * 16;
    int n = threadIdx.x;  // 256
    __shared__ __align__(16) float sc[16][64];
    for (int i = n; i < 1024; i += 256) sc[i >> 6][i & 63] = ctx[(b0 + (i >> 6)) * 64 + (i & 63)];
    __syncthreads();
    const float* wc = (dir ? Wihb : Wihf) + (size_t)n * 192 + 128;
    float bias = dir ? (bihb[n] + bhhb[n]) : (bihf[n] + bhhf[n]);
    float4 wreg[16];
    #pragma unroll
    for (int q = 0; q < 16; q++) wreg[q] = *(const float4*)(wc + q * 4);
    float* outp = ct_out + ((size_t)(dir * 8 + bgrp) * 256 + n) * 16;
    for (int s = 0; s < 16; s++) {
        float4 a = {0, 0, 0, 0};
        const float4* c4 = (const float4*)sc[s];
        #pragma unroll
        for (int q = 0; q < 16; q++) dot4(a, wreg[q], c4[q]);
        outp[s] = bias + a.x + a.y + a.z + a.w;
    }
}

// ---------------- K6: bidirectional LSTM, MFMA over 16 samples ----------------
__global__ __launch_bounds__(256, 1) void k_lstm(
    const float* __restrict__ gf_t, const float* __restrict__ gb_t,
    const float* __restrict__ cterm_all, const float* __restrict__ hinit,
    const unsigned short* __restrict__ whhf_bf, const unsigned short* __restrict__ whhb_bf,
    float* __restrict__ out0, float* __restrict__ out1) {
    int bx = blockIdx.x; int dir = bx >> 3; int bgrp = bx & 7; int b0 = bgrp * 16;
    int tid = threadIdx.x; int wave = tid >> 6; int lane = tid & 63;
    int r = lane & 15, kc = lane >> 4;
    const float* gsrc = dir ? gb_t : gf_t;
    const unsigned short* whhp = dir ? whhb_bf : whhf_bf;
    float* hall = dir ? out1 : out0;

    __shared__ float h_lds[64][17];
    __shared__ float g_lds[16][260];

    short8 wb0[4], wb1[4];
    f32x4 ct[4];
    {
        const float* cb = cterm_all + (size_t)(dir * 8 + bgrp) * 256 * 16;
        #pragma unroll
        for (int tt = 0; tt < 4; tt++) {
            int n = wave * 64 + tt * 16 + r;
            wb0[tt] = *(const short8*)(whhp + (size_t)n * 64 + kc * 8);
            wb1[tt] = *(const short8*)(whhp + (size_t)n * 64 + 32 + kc * 8);
            ct[tt] = *(const f32x4*)(cb + (size_t)n * 16 + kc * 4);
        }
    }
    int us = tid >> 4;
    int uv = (tid & 15) * 4;
    float cst[4];
    {
        float4 h0 = *(const float4*)(hinit + (size_t)(b0 + us) * 128 + dir * 64 + uv);
        cst[0] = ftanh(h0.x); cst[1] = ftanh(h0.y); cst[2] = ftanh(h0.z); cst[3] = ftanh(h0.w);
        h_lds[uv + 0][us] = h0.x; h_lds[uv + 1][us] = h0.y;
        h_lds[uv + 2][us] = h0.z; h_lds[uv + 3][us] = h0.w;
        int t0 = dir ? (NT - 1) : 0;
        *(float4*)(hall + ((size_t)(b0 + us) * NT + t0) * NV + uv) = h0;
    }
    const float* gbase = gsrc + (size_t)bgrp * NT * 256 * 16;
    f32x4 gc[4];
    {
        int tin = dir ? (NT - 1) : 0;
        #pragma unroll
        for (int tt = 0; tt < 4; tt++)
            gc[tt] = *(const f32x4*)(gbase + ((size_t)tin * 256 + wave * 64 + tt * 16 + r) * 16 + kc * 4);
    }
    __syncthreads();

    for (int s = 0; s < NT - 1; s++) {
        short8 a0, a1;
        #pragma unroll
        for (int j = 0; j < 8; j++) {
            a0[j] = (short)(__float_as_uint(h_lds[kc * 8 + j][r]) >> 16);
            a1[j] = (short)(__float_as_uint(h_lds[32 + kc * 8 + j][r]) >> 16);
        }
        int tnext = dir ? (NT - 2 - s) : (s + 1);
        f32x4 gn[4];
        #pragma unroll
        for (int tt = 0; tt < 4; tt++)
            gn[tt] = *(const f32x4*)(gbase + ((size_t)tnext * 256 + wave * 64 + tt * 16 + r) * 16 + kc * 4);
        #pragma unroll
        for (int tt = 0; tt < 4; tt++) {
            f32x4 acc = gc[tt] + ct[tt];
            acc = __builtin_amdgcn_mfma_f32_16x16x32_bf16(a0, wb0[tt], acc, 0, 0, 0);
            acc = __builtin_amdgcn_mfma_f32_16x16x32_bf16(a1, wb1[tt], acc, 0, 0, 0);
            int n = wave * 64 + tt * 16 + r;
            #pragma unroll
            for (int i = 0; i < 4; i++) g_lds[kc * 4 + i][n] = acc[i];
        }
        __syncthreads();
        {
            f32x4 gi = *(const f32x4*)&g_lds[us][uv];
            f32x4 gfv = *(const f32x4*)&g_lds[us][64 + uv];
            f32x4 ggv = *(const f32x4*)&g_lds[us][128 + uv];
            f32x4 gov = *(const f32x4*)&g_lds[us][192 + uv];
            float hv[4];
            #pragma unroll
            for (int j = 0; j < 4; j++) {
                cst[j] = fsigm(gfv[j]) * cst[j] + fsigm(gi[j]) * ftanh(ggv[j]);
                hv[j] = fsigm(gov[j]) * ftanh(cst[j]);
            }
            int tout = dir ? (NT - 2 - s) : (s + 1);
            float4 hnew; hnew.x = hv[0]; hnew.y = hv[1]; hnew.z = hv[2]; hnew.w = hv[3];
            *(float4*)(hall + ((size_t)(b0 + us) * NT + tout) * NV + uv) = hnew;
            h_lds[uv + 0][us] = hv[0]; h_lds[uv + 1][us] = hv[1];
            h_lds[uv + 2][us] = hv[2]; h_lds[uv + 3][us] = hv[3];
        }
        __syncthreads();
        #pragma unroll
        for (int tt = 0; tt < 4; tt++) gc[tt] = gn[tt];
    }
}

// ---------------- K_feat: fused per-feature MLP via bf16 MFMA ----------------
__global__ __launch_bounds__(256) void k_feat(
    const float* __restrict__ xcomp, const unsigned short* __restrict__ wbf,
    const float* __restrict__ wdiag, const float* __restrict__ bfeat,
    const float* __restrict__ Wnl1, const float* __restrict__ bnl1,
    const float* __restrict__ Wnl2, const float* __restrict__ bnl2,
    float* __restrict__ feat_out) {
    int wave = threadIdx.x >> 6; int lane = threadIdx.x & 63;
    int bt0 = blockIdx.x * 64 + wave * 16;
    int r = lane & 15, kc = lane >> 4;
    __shared__ __align__(16) unsigned short hb[4][16 * 32];
    __shared__ __align__(16) float ldsx[4][64 * 16];
    __shared__ __align__(16) float fl[4][16 * 65];
    unsigned short* hbw = hb[wave];
    float* lx = ldsx[wave];
    float* flw = fl[wave];

    short8 a0, a1;
    {
        const float* xr = xcomp + (size_t)(bt0 + r) * NV + kc * 8;
        a0 = pack8(*(const float4*)(xr), *(const float4*)(xr + 4));
        a1 = pack8(*(const float4*)(xr + 32), *(const float4*)(xr + 36));
    }
    {
        int gc0 = kc * 16;
        const float* xr2 = xcomp + (size_t)(bt0 + r) * NV + gc0;
        #pragma unroll
        for (int e = 0; e < 16; e += 4) {
            float4 p = *(const float4*)(xr2 + e);
            lx[(gc0 + e + 0) * 16 + r] = bf2f(f2bf(p.x));
            lx[(gc0 + e + 1) * 16 + r] = bf2f(f2bf(p.y));
            lx[(gc0 + e + 2) * 16 + r] = bf2f(f2bf(p.z));
            lx[(gc0 + e + 3) * 16 + r] = bf2f(f2bf(p.w));
        }
    }
    short8 wb0, wb1;
    {
        const float* w = Wnl1 + r * 32 + kc * 8;
        wb0 = pack8(*(const float4*)w, *(const float4*)(w + 4));
        const float* w2 = Wnl1 + (16 + r) * 32 + kc * 8;
        wb1 = pack8(*(const float4*)w2, *(const float4*)(w2 + 4));
    }
    float w2c0 = Wnl2[r], w2c1 = Wnl2[16 + r];
    float bn0 = bnl1[r], bn1 = bnl1[16 + r];
    float bn2 = bnl2[0];
    __builtin_amdgcn_wave_barrier();

    #pragma unroll 2
    for (int g = 0; g < 64; g++) {
        __builtin_amdgcn_wave_barrier();
        float xv[4];
        #pragma unroll
        for (int i = 0; i < 4; i++) xv[i] = lx[g * 16 + kc * 4 + i];
        float p[4] = {0.f, 0.f, 0.f, 0.f};
        #pragma unroll
        for (int f = 0; f < 2; f++) {
            int n0 = g * 32 + f * 16;
            const unsigned short* wrow = wbf + (size_t)(n0 + r) * 64;
            short8 b0 = *(const short8*)(wrow + kc * 8);
            short8 b1 = *(const short8*)(wrow + 32 + kc * 8);
            f32x4 acc = {0.f, 0.f, 0.f, 0.f};
            acc = __builtin_amdgcn_mfma_f32_16x16x32_bf16(a0, b0, acc, 0, 0, 0);
            acc = __builtin_amdgcn_mfma_f32_16x16x32_bf16(a1, b1, acc, 0, 0, 0);
            int n = n0 + r;
            float wd = wdiag[n], bs = bfeat[n];
            #pragma unroll
            for (int i = 0; i < 4; i++) {
                float h = acc[i] - xv[i] * wd + bs;
                h = fmaxf(h, 0.0f);
                hbw[(kc * 4 + i) * 32 + f * 16 + r] = f2bf(h);
            }
        }
        __builtin_amdgcn_wave_barrier();
        short8 ah = *(const short8*)(hbw + r * 32 + kc * 8);
        f32x4 z0 = {0.f, 0.f, 0.f, 0.f}, z1 = {0.f, 0.f, 0.f, 0.f};
        z0 = __builtin_amdgcn_mfma_f32_16x16x32_bf16(ah, wb0, z0, 0, 0, 0);
        z1 = __builtin_amdgcn_mfma_f32_16x16x32_bf16(ah, wb1, z1, 0, 0, 0);
        #pragma unroll
        for (int i = 0; i < 4; i++) {
            float za = fmaxf(z0[i] + bn0, 0.0f);
            float zb = fmaxf(z1[i] + bn1, 0.0f);
            p[i] = fmaf(za, w2c0, fmaf(zb, w2c1, p[i]));
        }
        #pragma unroll
        for (int m = 1; m < 16; m <<= 1) {
            #pragma unroll
            for (int i = 0; i < 4; i++) p[i] += __shfl_xor(p[i], m, 64);
        }
        if (r == 0) {
            #pragma unroll
            for (int i = 0; i < 4; i++) flw[(kc * 4 + i) * 65 + g] = p[i] + bn2;
        }
    }
    __builtin_amdgcn_wave_barrier();
    #pragma unroll
    for (int q = 0; q < 16; q++)
        feat_out[(size_t)(bt0 + q) * NV + lane] = flw[q * 65 + lane];
}

// ---------------- K7: rnn_imp = h_cat @ W_ri^T + b_ri ----------------
__global__ void k_rnnimp(const float* __restrict__ out0, const float* __restrict__ out1,
                         const float* __restrict__ Wri, const float* __restrict__ bri,
                         float* __restrict__ rnnraw) {
    int bt0 = blockIdx.x * 4;
    int tid = threadIdx.x;
    int rr = tid >> 6, v = tid & 63;
    __shared__ __align__(16) float hc[4][128];
    hc[rr][v] = out0[(size_t)(bt0 + rr) * NV + v];
    hc[rr][64 + v] = out1[(size_t)(bt0 + rr) * NV + v];
    __syncthreads();
    const float4* w = (const float4*)(Wri + (size_t)v * 128);
    const float4* h4 = (const float4*)hc[rr];
    float4 a = {0, 0, 0, 0};
    #pragma unroll
    for (int q = 0; q < 32; q++) dot4(a, w[q], h4[q]);
    rnnraw[(size_t)(bt0 + rr) * NV + v] = bri[v] + a.x + a.y + a.z + a.w;
}

// ---------------- K8: beta fusion + scale + write all 3 outputs ----------------
__global__ void k_final(const float* __restrict__ rnnraw, const float* __restrict__ gam,
                        const float* __restrict__ masks, const float* __restrict__ Wfu,
                        const float* __restrict__ bfu, const float* __restrict__ mmn_ws,
                        const float* __restrict__ minv, float* __restrict__ out0,
                        float* __restrict__ out1, float* __restrict__ out2) {
    int bt0 = blockIdx.x * 4; int tid = threadIdx.x;
    int rr = tid >> 6, v = tid & 63;
    __shared__ __align__(16) float gm[4][128];
    size_t row = (size_t)(bt0 + rr) * NV;
    gm[rr][v] = gam[row + v];
    gm[rr][64 + v] = masks[row + v];
    __syncthreads();
    const float4* w = (const float4*)(Wfu + (size_t)v * 128);
    const float4* x4 = (const float4*)gm[rr];
    float4 a = {0, 0, 0, 0};
    #pragma unroll
    for (int q = 0; q < 32; q++) dot4(a, w[q], x4[q]);
    float beta = sigm(bfu[v] + a.x + a.y + a.z + a.w);
    size_t idx = row + v;
    float rn = rnnraw[idx];
    float ft = out2[idx];
    float fin = beta * ft + (1.0f - beta) * rn;
    int b = (bt0 + rr) >> 8;
    float mm = mmn_ws[b * NV + v], mn = minv[b * NV + v];
    out0[idx] = fmaf(rn, mm, mn);
    out1[idx] = fmaf(ft, mm, mn);
    out2[idx] = fmaf(fin, mm, mn);
}

extern "C" void kernel_launch(void* const* d_in, const int* in_sizes, int n_in,
                              void* d_out, int out_size, void* d_ws, size_t ws_size,
                              hipStream_t stream) {
    const int*   lengths  = (const int*)d_in[0];
    const float* values   = (const float*)d_in[1];
    const float* masks    = (const float*)d_in[2];
    const float* deltas   = (const float*)d_in[3];
    const float* min_vals = (const float*)d_in[4];
    const float* max_vals = (const float*)d_in[5];
    const float* W_decay  = (const float*)d_in[6];
    const float* b_decay  = (const float*)d_in[7];
    const float* W_feat   = (const float*)d_in[8];
    const float* b_feat   = (const float*)d_in[9];
    const float* W_nl1    = (const float*)d_in[10];
    const float* b_nl1    = (const float*)d_in[11];
    const float* W_nl2    = (const float*)d_in[12];
    const float* b_nl2    = (const float*)d_in[13];
    const float* Wc1      = (const float*)d_in[14];
    const float* bc1      = (const float*)d_in[15];
    const float* Wc2      = (const float*)d_in[16];
    const float* bc2      = (const float*)d_in[17];
    const float* W_ih_g   = (const float*)d_in[18];
    const float* W_hh_g   = (const float*)d_in[19];
    const float* b_ih_g   = (const float*)d_in[20];
    const float* b_hh_g   = (const float*)d_in[21];
    const float* W_init   = (const float*)d_in[22];
    const float* b_init   = (const float*)d_in[23];
    const float* W_ih_f   = (const float*)d_in[24];
    const float* W_hh_f   = (const float*)d_in[25];
    const float* b_ih_f   = (const float*)d_in[26];
    const float* b_hh_f   = (const float*)d_in[27];
    const float* W_ih_b   = (const float*)d_in[28];
    const float* W_hh_b   = (const float*)d_in[29];
    const float* b_ih_b   = (const float*)d_in[30];
    const float* b_hh_b   = (const float*)d_in[31];
    const float* W_ri     = (const float*)d_in[32];
    const float* b_ri     = (const float*)d_in[33];
    const float* W_fu     = (const float*)d_in[34];
    const float* b_fu     = (const float*)d_in[35];

    float* ws = (float*)d_ws;
    float* xcomp  = ws;                     // 2097152
    float* gam    = ws + 2097152;           // 2097152
    float* rnnraw = ws + 4194304;           // 2097152
    float* stats  = ws + 6291456;           // 32768
    float* mmn    = ws + 6324224;           // 8192
    float* nmeans = ws + 6332416;           // 8192
    float* ctx    = ws + 6340608;           // 8192
    float* hinit  = ws + 6348800;           // 16384
    unsigned short* wbf = (unsigned short*)(ws + 6365184);     // 131072 u16
    float* wdiag  = ws + 6430720;           // 2048
    unsigned short* wgf = (unsigned short*)(ws + 6432768);     // 32768 u16
    unsigned short* wgb = (unsigned short*)(ws + 6449152);     // 32768 u16
    unsigned short* wgg = (unsigned short*)(ws + 6465536);     // 12288 u16
    unsigned short* whhf_bf = (unsigned short*)(ws + 6471680); // 16384 u16
    unsigned short* whhb_bf = (unsigned short*)(ws + 6479872); // 16384 u16
    unsigned short* whhg_bf = (unsigned short*)(ws + 6488064); // 3072 u16
    float* cterm  = ws + 6489600;           // 65536
    float* gates_f = ws + 6555136;          // 8388608
    float* gates_b = ws + 14943744;         // 8388608
    float* gates_g = ws + 23332352;         // 3145728  (end ~26.5M f32 ≈ 106 MB)

    float* out0 = (float*)d_out;
    float* out1 = out0 + NBTV;
    float* out2 = out0 + 2 * NBTV;

    k_conv<<<512, 256, 0, stream>>>(W_feat, W_ih_f, W_ih_b, W_ih_g, W_hh_f, W_hh_b, W_hh_g,
                                    wbf, wdiag, wgf, wgb, wgg, whhf_bf, whhb_bf, whhg_bf);
    k_stats<<<NB, 64, 0, stream>>>(lengths, values, masks, min_vals, max_vals, stats, mmn, nmeans);
    k_fill<<<NB, 64, 0, stream>>>(values, masks, deltas, min_vals, W_decay, b_decay, mmn, nmeans, xcomp, gam);
    k_gates<<<512, 256, 0, stream>>>(xcomp, masks, wgf, wgb, wgg, b_ih_g, gates_f, gates_b, gates_g);
    k_feat<<<NBT / 64, 256, 0, stream>>>(xcomp, wbf, wdiag, b_feat, W_nl1, b_nl1, W_nl2, b_nl2, out2);
    k_ctxmlp<<<NB, 64, 0, stream>>>(stats, Wc1, bc1, Wc2, bc2, ctx);
    k_gru<<<8, 256, 0, stream>>>(gates_g, lengths, whhg_bf, b_hh_g, ctx);
    k_hinit<<<NB, 128, 0, stream>>>(ctx, W_init, b_init, hinit);
    k_cterm<<<16, 256, 0, stream>>>(ctx, W_ih_f, W_ih_b, b_ih_f, b_hh_f, b_ih_b, b_hh_b, cterm);
    k_lstm<<<16, 256, 0, stream>>>(gates_f, gates_b, cterm, hinit, whhf_bf, whhb_bf, out0, out1);
    k_rnnimp<<<NBT / 4, 256, 0, stream>>>(out0, out1, W_ri, b_ri, rnnraw);
    k_final<<<NBT / 4, 256, 0, stream>>>(rnnraw, gam, masks, W_fu, b_fu, mmn, min_vals, out0, out1, out2);
}

// Round 5
// 833.877 us; speedup vs baseline: 1.0898x; 1.0898x over previous
//
#include <hip/hip_runtime.h>

static constexpr int NB = 128;
static constexpr int NT = 256;
static constexpr int NV = 64;
static constexpr int NBT = NB * NT;       // 32768
static constexpr int NBTV = NBT * NV;     // 2097152

typedef __attribute__((ext_vector_type(8))) short short8;
typedef __attribute__((ext_vector_type(4))) float f32x4;

__device__ __forceinline__ unsigned short f2bf(float x) {
    unsigned int u = __float_as_uint(x);
    return (unsigned short)((u + 0x7FFFu + ((u >> 16) & 1u)) >> 16);
}
__device__ __forceinline__ float bf2f(unsigned short b) {
    return __uint_as_float(((unsigned int)b) << 16);
}
__device__ __forceinline__ float sigm(float x) { return 1.0f / (1.0f + expf(-x)); }
__device__ __forceinline__ float fsigm(float x) {
    return __builtin_amdgcn_rcpf(1.0f + __expf(-x));
}
__device__ __forceinline__ float ftanh(float x) {
    return 1.0f - 2.0f * __builtin_amdgcn_rcpf(1.0f + __expf(2.0f * x));
}

__device__ __forceinline__ short8 pack8(float4 a, float4 b) {
    short8 r;
    r[0] = (short)f2bf(a.x); r[1] = (short)f2bf(a.y); r[2] = (short)f2bf(a.z); r[3] = (short)f2bf(a.w);
    r[4] = (short)f2bf(b.x); r[5] = (short)f2bf(b.y); r[6] = (short)f2bf(b.z); r[7] = (short)f2bf(b.w);
    return r;
}

__device__ __forceinline__ void dot4(float4& acc, const float4 wv, const float4 xv) {
    acc.x = fmaf(wv.x, xv.x, acc.x);
    acc.y = fmaf(wv.y, xv.y, acc.y);
    acc.z = fmaf(wv.z, xv.z, acc.z);
    acc.w = fmaf(wv.w, xv.w, acc.w);
}

// ---------------- K0: weight conversions to bf16 ----------------
__global__ void k_conv(const float* __restrict__ Wf, const float* __restrict__ Wihf,
                       const float* __restrict__ Wihb, const float* __restrict__ Wihg,
                       unsigned short* __restrict__ wbf, float* __restrict__ wdiag,
                       unsigned short* __restrict__ wgf, unsigned short* __restrict__ wgb,
                       unsigned short* __restrict__ wgg) {
    int i = blockIdx.x * 256 + threadIdx.x;
    if (i < NV * 32 * NV) wbf[i] = f2bf(Wf[i]);
    if (i < 2048) wdiag[i] = bf2f(f2bf(Wf[i * 64 + (i >> 5)]));
    if (i < 32768) {
        int n = i >> 7, k = i & 127;
        wgf[i] = f2bf(Wihf[n * 192 + k]);
        wgb[i] = f2bf(Wihb[n * 192 + k]);
    }
    if (i < 12288) wgg[i] = f2bf(Wihg[i]);
}

// ---------------- K1: per-(b,v) stats (4-way t-split) ----------------
__global__ __launch_bounds__(256) void k_stats(
    const int* __restrict__ lengths, const float* __restrict__ values,
    const float* __restrict__ masks, const float* __restrict__ minv,
    const float* __restrict__ maxv, float* __restrict__ stats,
    float* __restrict__ mmn_ws, float* __restrict__ nmeans_ws) {
    int b = blockIdx.x; int tid = threadIdx.x;
    int v = tid & 63; int tc = tid >> 6;
    const float* vp = values + (size_t)b * NT * NV;
    const float* mp = masks + (size_t)b * NT * NV;
    float sv = 0.f, sq = 0.f, sm = 0.f;
    for (int t = tc; t < NT; t += 4) {
        float x = vp[t * NV + v]; float m = mp[t * NV + v];
        sv += x; sq += x * x; sm += m;
    }
    __shared__ float red[3][4][64];
    red[0][tc][v] = sv; red[1][tc][v] = sq; red[2][tc][v] = sm;
    __syncthreads();
    if (tc == 0) {
        sv = red[0][0][v] + red[0][1][v] + red[0][2][v] + red[0][3][v];
        sq = red[1][0][v] + red[1][1][v] + red[1][2][v] + red[1][3][v];
        sm = red[2][0][v] + red[2][1][v] + red[2][2][v] + red[2][3][v];
        float mean = sv / sm;
        float var = (sq - 2.0f * mean * sv + (float)NT * mean * mean) / (sm - 1.0f);
        var = fmaxf(var, 0.0f);
        float sd = sqrtf(var);
        float lf = (float)lengths[b];
        float miss = 1.0f - sm / lf;
        float mn = minv[b * NV + v]; float mx = maxv[b * NV + v];
        float mm = fmaxf(mx - mn, 1e-8f);
        float* st = stats + b * 256;
        if (v == 0) st[0] = lf;
        st[1 + v] = mean; st[65 + v] = sd; st[129 + v] = miss;
        mmn_ws[b * NV + v] = mm;
        nmeans_ws[b * NV + v] = (mean - mn) / mm;
    }
}

// ---------------- K2: forward-fill (chunked scan) + decay + x_complete ----------------
__global__ __launch_bounds__(256) void k_fill(
    const float* __restrict__ values, const float* __restrict__ masks,
    const float* __restrict__ deltas, const float* __restrict__ minv,
    const float* __restrict__ Wd, const float* __restrict__ bd,
    const float* __restrict__ mmn_ws, const float* __restrict__ nmeans_ws,
    float* __restrict__ xcomp, float* __restrict__ gam) {
    int b = blockIdx.x; int tid = threadIdx.x;
    int v = tid & 63; int tc = tid >> 6;
    float mn = minv[b * NV + v];
    float mm = mmn_ws[b * NV + v];
    float nmean = nmeans_ws[b * NV + v];
    float wd = Wd[v * NV + v], bdv = bd[v];
    size_t base = (size_t)b * NT * NV + v;
    __shared__ float lastv[4][64];
    __shared__ int hasf[4][64];
    __shared__ float nv0s[64];
    int t0 = tc * 64;
    // phase 1: per-chunk last-observed nv
    float last = 0.f; int has = 0;
    for (int t = t0; t < t0 + 64; t++) {
        float val = values[base + (size_t)t * NV];
        float m = masks[base + (size_t)t * NV];
        float nv = (val - mn) / mm;
        if (m != 0.f) { last = nv; has = 1; }
        if (tc == 0 && t == 0) nv0s[v] = nv;
    }
    lastv[tc][v] = last; hasf[tc][v] = has;
    __syncthreads();
    // phase 2: carry into this chunk = last observed before t0, else nv[0]
    float xp = nv0s[v];
    for (int q = tc - 1; q >= 0; q--) {
        if (hasf[q][v]) { xp = lastv[q][v]; break; }
    }
    // phase 3: replay
    for (int t = t0; t < t0 + 64; t++) {
        size_t i = base + (size_t)t * NV;
        float val = values[i], m = masks[i], d = deltas[i];
        float nv = (val - mn) / mm;
        float g = expf(-fmaxf(fmaf(d, wd, bdv), 0.0f));
        float xd = g * xp + (1.0f - g) * nmean;
        float xc = m * nv + (1.0f - m) * xd;
        xcomp[i] = xc; gam[i] = g;
        xp = (m != 0.f) ? nv : xp;
    }
}

// ---------------- K_gates: MFMA GEMM for input-side gate projections ----------------
// gf/gb: [bt][64][4] (unit-major, gate-minor); gg: [bt][96] (b_ih_g folded in)
__global__ __launch_bounds__(256) void k_gates(
    const float* __restrict__ xcomp, const float* __restrict__ masks,
    const unsigned short* __restrict__ wgf, const unsigned short* __restrict__ wgb,
    const unsigned short* __restrict__ wgg, const float* __restrict__ bihg,
    float* __restrict__ gf, float* __restrict__ gb, float* __restrict__ gg) {
    int wave = threadIdx.x >> 6, lane = threadIdx.x & 63;
    int bt0 = blockIdx.x * 64 + wave * 16;
    int r = lane & 15, kc = lane >> 4;
    const float* xr = xcomp + (size_t)(bt0 + r) * NV + kc * 8;
    const float* mr = masks + (size_t)(bt0 + r) * NV + kc * 8;
    short8 af0 = pack8(*(const float4*)(xr), *(const float4*)(xr + 4));
    short8 af1 = pack8(*(const float4*)(xr + 32), *(const float4*)(xr + 36));
    short8 af2 = pack8(*(const float4*)(mr), *(const float4*)(mr + 4));
    short8 af3 = pack8(*(const float4*)(mr + 32), *(const float4*)(mr + 36));
    #pragma unroll 4
    for (int nt = 0; nt < 16; nt++) {
        const unsigned short* w = wgf + (size_t)(nt * 16 + r) * 128 + kc * 8;
        f32x4 acc = {0.f, 0.f, 0.f, 0.f};
        acc = __builtin_amdgcn_mfma_f32_16x16x32_bf16(af0, *(const short8*)(w), acc, 0, 0, 0);
        acc = __builtin_amdgcn_mfma_f32_16x16x32_bf16(af1, *(const short8*)(w + 32), acc, 0, 0, 0);
        acc = __builtin_amdgcn_mfma_f32_16x16x32_bf16(af2, *(const short8*)(w + 64), acc, 0, 0, 0);
        acc = __builtin_amdgcn_mfma_f32_16x16x32_bf16(af3, *(const short8*)(w + 96), acc, 0, 0, 0);
        int col = nt * 16 + r, g = col >> 6, n = col & 63;
        #pragma unroll
        for (int i = 0; i < 4; i++)
            gf[((size_t)(bt0 + kc * 4 + i) * 64 + n) * 4 + g] = acc[i];
    }
    #pragma unroll 4
    for (int nt = 0; nt < 16; nt++) {
        const unsigned short* w = wgb + (size_t)(nt * 16 + r) * 128 + kc * 8;
        f32x4 acc = {0.f, 0.f, 0.f, 0.f};
        acc = __builtin_amdgcn_mfma_f32_16x16x32_bf16(af0, *(const short8*)(w), acc, 0, 0, 0);
        acc = __builtin_amdgcn_mfma_f32_16x16x32_bf16(af1, *(const short8*)(w + 32), acc, 0, 0, 0);
        acc = __builtin_amdgcn_mfma_f32_16x16x32_bf16(af2, *(const short8*)(w + 64), acc, 0, 0, 0);
        acc = __builtin_amdgcn_mfma_f32_16x16x32_bf16(af3, *(const short8*)(w + 96), acc, 0, 0, 0);
        int col = nt * 16 + r, g = col >> 6, n = col & 63;
        #pragma unroll
        for (int i = 0; i < 4; i++)
            gb[((size_t)(bt0 + kc * 4 + i) * 64 + n) * 4 + g] = acc[i];
    }
    #pragma unroll 3
    for (int nt = 0; nt < 6; nt++) {
        const unsigned short* w = wgg + (size_t)(nt * 16 + r) * 128 + kc * 8;
        float bias = bihg[nt * 16 + r];
        f32x4 acc = {bias, bias, bias, bias};
        acc = __builtin_amdgcn_mfma_f32_16x16x32_bf16(af0, *(const short8*)(w), acc, 0, 0, 0);
        acc = __builtin_amdgcn_mfma_f32_16x16x32_bf16(af1, *(const short8*)(w + 32), acc, 0, 0, 0);
        acc = __builtin_amdgcn_mfma_f32_16x16x32_bf16(af2, *(const short8*)(w + 64), acc, 0, 0, 0);
        acc = __builtin_amdgcn_mfma_f32_16x16x32_bf16(af3, *(const short8*)(w + 96), acc, 0, 0, 0);
        #pragma unroll
        for (int i = 0; i < 4; i++)
            gg[(size_t)(bt0 + kc * 4 + i) * 96 + nt * 16 + r] = acc[i];
    }
}

// ---------------- K3: ctx MLP ----------------
__global__ void k_ctxmlp(const float* __restrict__ stats, const float* __restrict__ Wc1,
                         const float* __restrict__ bc1, const float* __restrict__ Wc2,
                         const float* __restrict__ bc2, float* __restrict__ ctx) {
    int b = blockIdx.x, tid = threadIdx.x;  // 64 threads
    __shared__ float lw[64 * 193];
    __shared__ float ss[193];
    __shared__ float h1[64];
    for (int i = tid; i < 64 * 193; i += 64) lw[i] = Wc1[i];
    ss[tid] = stats[b * 256 + tid];
    ss[64 + tid] = stats[b * 256 + 64 + tid];
    ss[128 + tid] = stats[b * 256 + 128 + tid];
    if (tid == 0) ss[192] = stats[b * 256 + 192];
    __syncthreads();
    float acc = bc1[tid];
    const float* w = lw + tid * 193;
    for (int k = 0; k < 193; k++) acc = fmaf(w[k], ss[k], acc);
    h1[tid] = fmaxf(acc, 0.f);
    __syncthreads();
    if (tid < 32) {
        float a = bc2[tid];
        const float* w2 = Wc2 + tid * 64;
        for (int k = 0; k < 64; k++) a = fmaf(w2[k], h1[k], a);
        ctx[b * 64 + tid] = a;
    }
}

// ---------------- K4: GRU — 1 wave = 2 samples, weights in VGPRs, f32 ----------------
__global__ __launch_bounds__(64, 1) void k_gru(
    const float* __restrict__ gg_t, const int* __restrict__ lengths,
    const float* __restrict__ Whhg, const float* __restrict__ bhh,
    float* __restrict__ ctx) {
    int b0 = blockIdx.x * 2;
    int lane = threadIdx.x;
    int s = lane >> 5, n = lane & 31;
    int b = b0 + s;
    __shared__ __align__(16) float h_lds[2][32];
    float4 w[24];
    float bh[3];
    #pragma unroll
    for (int g = 0; g < 3; g++) {
        #pragma unroll
        for (int q = 0; q < 8; q++)
            w[g * 8 + q] = *(const float4*)(Whhg + (size_t)(g * 32 + n) * 32 + q * 4);
        bh[g] = bhh[g * 32 + n];
    }
    int len = lengths[b];
    float hprev = 0.f, hn = 0.f;
    h_lds[s][n] = 0.f;
    const float* gbase = gg_t + (size_t)b * NT * 96;
    float gc0 = gbase[n], gc1 = gbase[32 + n], gc2 = gbase[64 + n];
    __syncthreads();
    for (int t = 0; t < NT; t++) {
        float4 ar = {0, 0, 0, 0}, az = {0, 0, 0, 0}, an = {0, 0, 0, 0};
        const float4* h4 = (const float4*)h_lds[s];
        #pragma unroll
        for (int q = 0; q < 8; q++) {
            float4 hq = h4[q];
            dot4(ar, w[q], hq);
            dot4(az, w[8 + q], hq);
            dot4(an, w[16 + q], hq);
        }
        float gn0 = 0.f, gn1 = 0.f, gn2 = 0.f;
        if (t + 1 < NT) {
            const float* gt = gbase + (size_t)(t + 1) * 96;
            gn0 = gt[n]; gn1 = gt[32 + n]; gn2 = gt[64 + n];
        }
        float hr = bh[0] + ar.x + ar.y + ar.z + ar.w;
        float hz = bh[1] + az.x + az.y + az.z + az.w;
        float hnn = bh[2] + an.x + an.y + an.z + an.w;
        float rr = fsigm(gc0 + hr);
        float zz = fsigm(gc1 + hz);
        float nn = ftanh(gc2 + rr * hnn);
        float h = (1.f - zz) * nn + zz * hprev;
        hprev = h;
        if (t < len) hn = h;
        __syncthreads();
        h_lds[s][n] = h;
        __syncthreads();
        gc0 = gn0; gc1 = gn1; gc2 = gn2;
    }
    ctx[b * 64 + 32 + n] = hn;
}

// ---------------- K5: hinit ----------------
__global__ void k_hinit(const float* __restrict__ ctx, const float* __restrict__ Wi,
                        const float* __restrict__ bi, float* __restrict__ hinit) {
    int b = blockIdx.x; int j = threadIdx.x;  // 128
    __shared__ __align__(16) float sc[64];
    if (j < 64) sc[j] = ctx[b * 64 + j];
    __syncthreads();
    const float4* w = (const float4*)(Wi + (size_t)j * 64);
    const float4* c4 = (const float4*)sc;
    float4 a = {0, 0, 0, 0};
    #pragma unroll
    for (int q = 0; q < 16; q++) dot4(a, w[q], c4[q]);
    hinit[b * 128 + j] = bi[j] + a.x + a.y + a.z + a.w;
}

// ---------------- K_cterm: ctx-part of LSTM gates + biases, [dir*128+b][64][4] ----------------
__global__ void k_cterm(const float* __restrict__ ctx,
                        const float* __restrict__ Wihf, const float* __restrict__ Wihb,
                        const float* __restrict__ bihf, const float* __restrict__ bhhf,
                        const float* __restrict__ bihb, const float* __restrict__ bhhb,
                        float* __restrict__ ct_out) {
    int bx = blockIdx.x; int dir = bx >> 7; int b = bx & 127;
    int col = threadIdx.x;  // 256 (gate-major row of Wih)
    __shared__ __align__(16) float sc[64];
    if (col < 64) sc[col] = ctx[b * 64 + col];
    __syncthreads();
    const float* wc = (dir ? Wihb : Wihf) + (size_t)col * 192 + 128;
    float bias = dir ? (bihb[col] + bhhb[col]) : (bihf[col] + bhhf[col]);
    const float4* c4 = (const float4*)sc;
    float4 a = {0, 0, 0, 0};
    #pragma unroll
    for (int q = 0; q < 16; q++) dot4(a, *(const float4*)(wc + q * 4), c4[q]);
    int g = col >> 6, n = col & 63;
    ct_out[((size_t)bx * 64 + n) * 4 + g] = bias + a.x + a.y + a.z + a.w;
}

// ---------------- K6: LSTM — 1 wave = 1 (sample,dir), Whh f32 in VGPRs ----------------
__global__ __launch_bounds__(64, 1) void k_lstm(
    const float* __restrict__ gf, const float* __restrict__ gb,
    const float* __restrict__ cterm, const float* __restrict__ hinit,
    const float* __restrict__ Whhf, const float* __restrict__ Whhb,
    float* __restrict__ out0, float* __restrict__ out1) {
    int bx = blockIdx.x; int dir = bx >> 7; int b = bx & 127;
    int n = threadIdx.x;  // 64
    const float* gates = dir ? gb : gf;
    const float* Whh = dir ? Whhb : Whhf;
    float* hall = dir ? out1 : out0;
    __shared__ __align__(16) float h_lds[64];
    float4 w[64];
    #pragma unroll
    for (int g = 0; g < 4; g++) {
        #pragma unroll
        for (int q = 0; q < 16; q++)
            w[g * 16 + q] = *(const float4*)(Whh + (size_t)(g * 64 + n) * 64 + q * 4);
    }
    float4 ctg = *(const float4*)(cterm + ((size_t)bx * 64 + n) * 4);
    float c;
    {
        float h0 = hinit[b * 128 + dir * 64 + n];
        c = ftanh(h0);
        h_lds[n] = h0;
        int t0 = dir ? (NT - 1) : 0;
        hall[((size_t)b * NT + t0) * NV + n] = h0;
    }
    size_t gbase = (size_t)b * NT * 256;  // [t][64][4]
    int tin0 = dir ? (NT - 1) : 0;
    float4 gc = *(const float4*)(gates + gbase + (size_t)tin0 * 256 + n * 4);
    __syncthreads();
    for (int s = 0; s < NT - 1; s++) {
        float4 ai = {0, 0, 0, 0}, af = {0, 0, 0, 0}, ag = {0, 0, 0, 0}, ao = {0, 0, 0, 0};
        const float4* h4 = (const float4*)h_lds;
        #pragma unroll
        for (int q = 0; q < 16; q++) {
            float4 hq = h4[q];
            dot4(ai, w[q], hq);
            dot4(af, w[16 + q], hq);
            dot4(ag, w[32 + q], hq);
            dot4(ao, w[48 + q], hq);
        }
        int tnext = dir ? (NT - 2 - s) : (s + 1);
        float4 gn = *(const float4*)(gates + gbase + (size_t)tnext * 256 + n * 4);
        float ii = fsigm(gc.x + ctg.x + ai.x + ai.y + ai.z + ai.w);
        float ff = fsigm(gc.y + ctg.y + af.x + af.y + af.z + af.w);
        float gv = ftanh(gc.z + ctg.z + ag.x + ag.y + ag.z + ag.w);
        float oo = fsigm(gc.w + ctg.w + ao.x + ao.y + ao.z + ao.w);
        c = ff * c + ii * gv;
        float hv = oo * ftanh(c);
        int tout = dir ? (NT - 2 - s) : (s + 1);
        hall[((size_t)b * NT + tout) * NV + n] = hv;
        __syncthreads();
        h_lds[n] = hv;
        __syncthreads();
        gc = gn;
    }
}

// ---------------- K_feat: fused per-feature MLP via bf16 MFMA ----------------
__global__ __launch_bounds__(256) void k_feat(
    const float* __restrict__ xcomp, const unsigned short* __restrict__ wbf,
    const float* __restrict__ wdiag, const float* __restrict__ bfeat,
    const float* __restrict__ Wnl1, const float* __restrict__ bnl1,
    const float* __restrict__ Wnl2, const float* __restrict__ bnl2,
    float* __restrict__ feat_out) {
    int wave = threadIdx.x >> 6; int lane = threadIdx.x & 63;
    int bt0 = blockIdx.x * 64 + wave * 16;
    int r = lane & 15, kc = lane >> 4;
    __shared__ __align__(16) unsigned short hb[4][16 * 32];
    __shared__ __align__(16) float ldsx[4][64 * 16];
    __shared__ __align__(16) float fl[4][16 * 65];
    unsigned short* hbw = hb[wave];
    float* lx = ldsx[wave];
    float* flw = fl[wave];

    short8 a0, a1;
    {
        const float* xr = xcomp + (size_t)(bt0 + r) * NV + kc * 8;
        a0 = pack8(*(const float4*)(xr), *(const float4*)(xr + 4));
        a1 = pack8(*(const float4*)(xr + 32), *(const float4*)(xr + 36));
    }
    {
        int gc0 = kc * 16;
        const float* xr2 = xcomp + (size_t)(bt0 + r) * NV + gc0;
        #pragma unroll
        for (int e = 0; e < 16; e += 4) {
            float4 p = *(const float4*)(xr2 + e);
            lx[(gc0 + e + 0) * 16 + r] = bf2f(f2bf(p.x));
            lx[(gc0 + e + 1) * 16 + r] = bf2f(f2bf(p.y));
            lx[(gc0 + e + 2) * 16 + r] = bf2f(f2bf(p.z));
            lx[(gc0 + e + 3) * 16 + r] = bf2f(f2bf(p.w));
        }
    }
    short8 wb0, wb1;
    {
        const float* w = Wnl1 + r * 32 + kc * 8;
        wb0 = pack8(*(const float4*)w, *(const float4*)(w + 4));
        const float* w2 = Wnl1 + (16 + r) * 32 + kc * 8;
        wb1 = pack8(*(const float4*)w2, *(const float4*)(w2 + 4));
    }
    float w2c0 = Wnl2[r], w2c1 = Wnl2[16 + r];
    float bn0 = bnl1[r], bn1 = bnl1[16 + r];
    float bn2 = bnl2[0];
    __builtin_amdgcn_wave_barrier();

    #pragma unroll 2
    for (int g = 0; g < 64; g++) {
        __builtin_amdgcn_wave_barrier();
        float xv[4];
        #pragma unroll
        for (int i = 0; i < 4; i++) xv[i] = lx[g * 16 + kc * 4 + i];
        float p[4] = {0.f, 0.f, 0.f, 0.f};
        #pragma unroll
        for (int f = 0; f < 2; f++) {
            int n0 = g * 32 + f * 16;
            const unsigned short* wrow = wbf + (size_t)(n0 + r) * 64;
            short8 b0 = *(const short8*)(wrow + kc * 8);
            short8 b1 = *(const short8*)(wrow + 32 + kc * 8);
            f32x4 acc = {0.f, 0.f, 0.f, 0.f};
            acc = __builtin_amdgcn_mfma_f32_16x16x32_bf16(a0, b0, acc, 0, 0, 0);
            acc = __builtin_amdgcn_mfma_f32_16x16x32_bf16(a1, b1, acc, 0, 0, 0);
            int n = n0 + r;
            float wd = wdiag[n], bs = bfeat[n];
            #pragma unroll
            for (int i = 0; i < 4; i++) {
                float h = acc[i] - xv[i] * wd + bs;
                h = fmaxf(h, 0.0f);
                hbw[(kc * 4 + i) * 32 + f * 16 + r] = f2bf(h);
            }
        }
        __builtin_amdgcn_wave_barrier();
        short8 ah = *(const short8*)(hbw + r * 32 + kc * 8);
        f32x4 z0 = {0.f, 0.f, 0.f, 0.f}, z1 = {0.f, 0.f, 0.f, 0.f};
        z0 = __builtin_amdgcn_mfma_f32_16x16x32_bf16(ah, wb0, z0, 0, 0, 0);
        z1 = __builtin_amdgcn_mfma_f32_16x16x32_bf16(ah, wb1, z1, 0, 0, 0);
        #pragma unroll
        for (int i = 0; i < 4; i++) {
            float za = fmaxf(z0[i] + bn0, 0.0f);
            float zb = fmaxf(z1[i] + bn1, 0.0f);
            p[i] = fmaf(za, w2c0, fmaf(zb, w2c1, p[i]));
        }
        #pragma unroll
        for (int m = 1; m < 16; m <<= 1) {
            #pragma unroll
            for (int i = 0; i < 4; i++) p[i] += __shfl_xor(p[i], m, 64);
        }
        if (r == 0) {
            #pragma unroll
            for (int i = 0; i < 4; i++) flw[(kc * 4 + i) * 65 + g] = p[i] + bn2;
        }
    }
    __builtin_amdgcn_wave_barrier();
    #pragma unroll
    for (int q = 0; q < 16; q++)
        feat_out[(size_t)(bt0 + q) * NV + lane] = flw[q * 65 + lane];
}

// ---------------- K7: rnn_imp = h_cat @ W_ri^T + b_ri ----------------
__global__ void k_rnnimp(const float* __restrict__ out0, const float* __restrict__ out1,
                         const float* __restrict__ Wri, const float* __restrict__ bri,
                         float* __restrict__ rnnraw) {
    int bt0 = blockIdx.x * 4;
    int tid = threadIdx.x;
    int rr = tid >> 6, v = tid & 63;
    __shared__ __align__(16) float hc[4][128];
    hc[rr][v] = out0[(size_t)(bt0 + rr) * NV + v];
    hc[rr][64 + v] = out1[(size_t)(bt0 + rr) * NV + v];
    __syncthreads();
    const float4* w = (const float4*)(Wri + (size_t)v * 128);
    const float4* h4 = (const float4*)hc[rr];
    float4 a = {0, 0, 0, 0};
    #pragma unroll
    for (int q = 0; q < 32; q++) dot4(a, w[q], h4[q]);
    rnnraw[(size_t)(bt0 + rr) * NV + v] = bri[v] + a.x + a.y + a.z + a.w;
}

// ---------------- K8: beta fusion + scale + write all 3 outputs ----------------
__global__ void k_final(const float* __restrict__ rnnraw, const float* __restrict__ gam,
                        const float* __restrict__ masks, const float* __restrict__ Wfu,
                        const float* __restrict__ bfu, const float* __restrict__ mmn_ws,
                        const float* __restrict__ minv, float* __restrict__ out0,
                        float* __restrict__ out1, float* __restrict__ out2) {
    int bt0 = blockIdx.x * 4; int tid = threadIdx.x;
    int rr = tid >> 6, v = tid & 63;
    __shared__ __align__(16) float gm[4][128];
    size_t row = (size_t)(bt0 + rr) * NV;
    gm[rr][v] = gam[row + v];
    gm[rr][64 + v] = masks[row + v];
    __syncthreads();
    const float4* w = (const float4*)(Wfu + (size_t)v * 128);
    const float4* x4 = (const float4*)gm[rr];
    float4 a = {0, 0, 0, 0};
    #pragma unroll
    for (int q = 0; q < 32; q++) dot4(a, w[q], x4[q]);
    float beta = sigm(bfu[v] + a.x + a.y + a.z + a.w);
    size_t idx = row + v;
    float rn = rnnraw[idx];
    float ft = out2[idx];
    float fin = beta * ft + (1.0f - beta) * rn;
    int b = (bt0 + rr) >> 8;
    float mm = mmn_ws[b * NV + v], mn = minv[b * NV + v];
    out0[idx] = fmaf(rn, mm, mn);
    out1[idx] = fmaf(ft, mm, mn);
    out2[idx] = fmaf(fin, mm, mn);
}

extern "C" void kernel_launch(void* const* d_in, const int* in_sizes, int n_in,
                              void* d_out, int out_size, void* d_ws, size_t ws_size,
                              hipStream_t stream) {
    const int*   lengths  = (const int*)d_in[0];
    const float* values   = (const float*)d_in[1];
    const float* masks    = (const float*)d_in[2];
    const float* deltas   = (const float*)d_in[3];
    const float* min_vals = (const float*)d_in[4];
    const float* max_vals = (const float*)d_in[5];
    const float* W_decay  = (const float*)d_in[6];
    const float* b_decay  = (const float*)d_in[7];
    const float* W_feat   = (const float*)d_in[8];
    const float* b_feat   = (const float*)d_in[9];
    const float* W_nl1    = (const float*)d_in[10];
    const float* b_nl1    = (const float*)d_in[11];
    const float* W_nl2    = (const float*)d_in[12];
    const float* b_nl2    = (const float*)d_in[13];
    const float* Wc1      = (const float*)d_in[14];
    const float* bc1      = (const float*)d_in[15];
    const float* Wc2      = (const float*)d_in[16];
    const float* bc2      = (const float*)d_in[17];
    const float* W_ih_g   = (const float*)d_in[18];
    const float* W_hh_g   = (const float*)d_in[19];
    const float* b_ih_g   = (const float*)d_in[20];
    const float* b_hh_g   = (const float*)d_in[21];
    const float* W_init   = (const float*)d_in[22];
    const float* b_init   = (const float*)d_in[23];
    const float* W_ih_f   = (const float*)d_in[24];
    const float* W_hh_f   = (const float*)d_in[25];
    const float* b_ih_f   = (const float*)d_in[26];
    const float* b_hh_f   = (const float*)d_in[27];
    const float* W_ih_b   = (const float*)d_in[28];
    const float* W_hh_b   = (const float*)d_in[29];
    const float* b_ih_b   = (const float*)d_in[30];
    const float* b_hh_b   = (const float*)d_in[31];
    const float* W_ri     = (const float*)d_in[32];
    const float* b_ri     = (const float*)d_in[33];
    const float* W_fu     = (const float*)d_in[34];
    const float* b_fu     = (const float*)d_in[35];

    float* ws = (float*)d_ws;
    float* xcomp  = ws;                     // 2097152
    float* gam    = ws + 2097152;           // 2097152
    float* rnnraw = ws + 4194304;           // 2097152
    float* stats  = ws + 6291456;           // 32768
    float* mmn    = ws + 6324224;           // 8192
    float* nmeans = ws + 6332416;           // 8192
    float* ctx    = ws + 6340608;           // 8192
    float* hinit  = ws + 6348800;           // 16384
    unsigned short* wbf = (unsigned short*)(ws + 6365184);  // 131072 u16
    float* wdiag  = ws + 6430720;           // 2048
    unsigned short* wgf = (unsigned short*)(ws + 6432768);  // 32768 u16
    unsigned short* wgb = (unsigned short*)(ws + 6449152);  // 32768 u16
    unsigned short* wgg = (unsigned short*)(ws + 6465536);  // 12288 u16
    float* cterm  = ws + 6471680;           // 65536
    float* gates_f = ws + 6537216;          // 8388608
    float* gates_b = ws + 14925824;         // 8388608
    float* gates_g = ws + 23314432;         // 3145728  (end ≈ 105.8 MB)

    float* out0 = (float*)d_out;
    float* out1 = out0 + NBTV;
    float* out2 = out0 + 2 * NBTV;

    k_conv<<<512, 256, 0, stream>>>(W_feat, W_ih_f, W_ih_b, W_ih_g, wbf, wdiag, wgf, wgb, wgg);
    k_stats<<<NB, 256, 0, stream>>>(lengths, values, masks, min_vals, max_vals, stats, mmn, nmeans);
    k_fill<<<NB, 256, 0, stream>>>(values, masks, deltas, min_vals, W_decay, b_decay, mmn, nmeans, xcomp, gam);
    k_gates<<<NBT / 64, 256, 0, stream>>>(xcomp, masks, wgf, wgb, wgg, b_ih_g, gates_f, gates_b, gates_g);
    k_feat<<<NBT / 64, 256, 0, stream>>>(xcomp, wbf, wdiag, b_feat, W_nl1, b_nl1, W_nl2, b_nl2, out2);
    k_ctxmlp<<<NB, 64, 0, stream>>>(stats, Wc1, bc1, Wc2, bc2, ctx);
    k_gru<<<64, 64, 0, stream>>>(gates_g, lengths, W_hh_g, b_hh_g, ctx);
    k_hinit<<<NB, 128, 0, stream>>>(ctx, W_init, b_init, hinit);
    k_cterm<<<256, 256, 0, stream>>>(ctx, W_ih_f, W_ih_b, b_ih_f, b_hh_f, b_ih_b, b_hh_b, cterm);
    k_lstm<<<256, 64, 0, stream>>>(gates_f, gates_b, cterm, hinit, W_hh_f, W_hh_b, out0, out1);
    k_rnnimp<<<NBT / 4, 256, 0, stream>>>(out0, out1, W_ri, b_ri, rnnraw);
    k_final<<<NBT / 4, 256, 0, stream>>>(rnnraw, gam, masks, W_fu, b_fu, mmn, min_vals, out0, out1, out2);
}

// Round 6
// 653.997 us; speedup vs baseline: 1.3895x; 1.2750x over previous
//
#include <hip/hip_runtime.h>

static constexpr int NB = 128;
static constexpr int NT = 256;
static constexpr int NV = 64;
static constexpr int NBT = NB * NT;       // 32768
static constexpr int NBTV = NBT * NV;     // 2097152

typedef __attribute__((ext_vector_type(8))) short short8;
typedef __attribute__((ext_vector_type(4))) float f32x4;
typedef __attribute__((ext_vector_type(4))) float fvec4;
typedef __attribute__((ext_vector_type(2))) _Float16 f16x2;

union WU { fvec4 f4; f16x2 h[4]; };

#if defined(__has_builtin)
#if __has_builtin(__builtin_amdgcn_fdot2)
#define HAS_FDOT2 1
#endif
#endif

__device__ __forceinline__ float dot2acc(f16x2 a, f16x2 b, float c) {
#ifdef HAS_FDOT2
    return __builtin_amdgcn_fdot2(a, b, c, false);
#else
    return c + (float)a[0] * (float)b[0] + (float)a[1] * (float)b[1];
#endif
}

__device__ __forceinline__ unsigned short f2bf(float x) {
    unsigned int u = __float_as_uint(x);
    return (unsigned short)((u + 0x7FFFu + ((u >> 16) & 1u)) >> 16);
}
__device__ __forceinline__ float bf2f(unsigned short b) {
    return __uint_as_float(((unsigned int)b) << 16);
}
__device__ __forceinline__ unsigned short f2h(float x) {
    union { _Float16 h; unsigned short u; } c; c.h = (_Float16)x; return c.u;
}
__device__ __forceinline__ float sigm(float x) { return 1.0f / (1.0f + expf(-x)); }
__device__ __forceinline__ float fsigm(float x) {
    return __builtin_amdgcn_rcpf(1.0f + __expf(-x));
}
__device__ __forceinline__ float ftanh(float x) {
    return 1.0f - 2.0f * __builtin_amdgcn_rcpf(1.0f + __expf(2.0f * x));
}

__device__ __forceinline__ short8 pack8(float4 a, float4 b) {
    short8 r;
    r[0] = (short)f2bf(a.x); r[1] = (short)f2bf(a.y); r[2] = (short)f2bf(a.z); r[3] = (short)f2bf(a.w);
    r[4] = (short)f2bf(b.x); r[5] = (short)f2bf(b.y); r[6] = (short)f2bf(b.z); r[7] = (short)f2bf(b.w);
    return r;
}

__device__ __forceinline__ void dot4(float4& acc, const float4 wv, const float4 xv) {
    acc.x = fmaf(wv.x, xv.x, acc.x);
    acc.y = fmaf(wv.y, xv.y, acc.y);
    acc.z = fmaf(wv.z, xv.z, acc.z);
    acc.w = fmaf(wv.w, xv.w, acc.w);
}

// ---------------- K0: weight conversions ----------------
__global__ void k_conv(const float* __restrict__ Wf, const float* __restrict__ Wihf,
                       const float* __restrict__ Wihb, const float* __restrict__ Wihg,
                       const float* __restrict__ Whhf, const float* __restrict__ Whhb,
                       const float* __restrict__ Whhg,
                       unsigned short* __restrict__ wbf, float* __restrict__ wdiag,
                       unsigned short* __restrict__ wgf, unsigned short* __restrict__ wgb,
                       unsigned short* __restrict__ wgg,
                       unsigned short* __restrict__ whhf_h, unsigned short* __restrict__ whhb_h,
                       unsigned short* __restrict__ whhg_h) {
    int i = blockIdx.x * 256 + threadIdx.x;
    if (i < NV * 32 * NV) wbf[i] = f2bf(Wf[i]);
    if (i < 2048) wdiag[i] = bf2f(f2bf(Wf[i * 64 + (i >> 5)]));
    if (i < 32768) {
        int n = i >> 7, k = i & 127;
        wgf[i] = f2bf(Wihf[n * 192 + k]);
        wgb[i] = f2bf(Wihb[n * 192 + k]);
    }
    if (i < 12288) wgg[i] = f2bf(Wihg[i]);
    if (i < 16384) { whhf_h[i] = f2h(Whhf[i]); whhb_h[i] = f2h(Whhb[i]); }
    if (i < 3072) whhg_h[i] = f2h(Whhg[i]);
}

// ---------------- K1: per-(b,v) stats (4-way t-split) ----------------
__global__ __launch_bounds__(256) void k_stats(
    const int* __restrict__ lengths, const float* __restrict__ values,
    const float* __restrict__ masks, const float* __restrict__ minv,
    const float* __restrict__ maxv, float* __restrict__ stats,
    float* __restrict__ mmn_ws, float* __restrict__ nmeans_ws) {
    int b = blockIdx.x; int tid = threadIdx.x;
    int v = tid & 63; int tc = tid >> 6;
    const float* vp = values + (size_t)b * NT * NV;
    const float* mp = masks + (size_t)b * NT * NV;
    float sv = 0.f, sq = 0.f, sm = 0.f;
    for (int t = tc; t < NT; t += 4) {
        float x = vp[t * NV + v]; float m = mp[t * NV + v];
        sv += x; sq += x * x; sm += m;
    }
    __shared__ float red[3][4][64];
    red[0][tc][v] = sv; red[1][tc][v] = sq; red[2][tc][v] = sm;
    __syncthreads();
    if (tc == 0) {
        sv = red[0][0][v] + red[0][1][v] + red[0][2][v] + red[0][3][v];
        sq = red[1][0][v] + red[1][1][v] + red[1][2][v] + red[1][3][v];
        sm = red[2][0][v] + red[2][1][v] + red[2][2][v] + red[2][3][v];
        float mean = sv / sm;
        float var = (sq - 2.0f * mean * sv + (float)NT * mean * mean) / (sm - 1.0f);
        var = fmaxf(var, 0.0f);
        float sd = sqrtf(var);
        float lf = (float)lengths[b];
        float miss = 1.0f - sm / lf;
        float mn = minv[b * NV + v]; float mx = maxv[b * NV + v];
        float mm = fmaxf(mx - mn, 1e-8f);
        float* st = stats + b * 256;
        if (v == 0) st[0] = lf;
        st[1 + v] = mean; st[65 + v] = sd; st[129 + v] = miss;
        mmn_ws[b * NV + v] = mm;
        nmeans_ws[b * NV + v] = (mean - mn) / mm;
    }
}

// ---------------- K2: forward-fill (chunked scan) + decay + x_complete ----------------
__global__ __launch_bounds__(256) void k_fill(
    const float* __restrict__ values, const float* __restrict__ masks,
    const float* __restrict__ deltas, const float* __restrict__ minv,
    const float* __restrict__ Wd, const float* __restrict__ bd,
    const float* __restrict__ mmn_ws, const float* __restrict__ nmeans_ws,
    float* __restrict__ xcomp, float* __restrict__ gam) {
    int b = blockIdx.x; int tid = threadIdx.x;
    int v = tid & 63; int tc = tid >> 6;
    float mn = minv[b * NV + v];
    float mm = mmn_ws[b * NV + v];
    float nmean = nmeans_ws[b * NV + v];
    float wd = Wd[v * NV + v], bdv = bd[v];
    size_t base = (size_t)b * NT * NV + v;
    __shared__ float lastv[4][64];
    __shared__ int hasf[4][64];
    __shared__ float nv0s[64];
    int t0 = tc * 64;
    float last = 0.f; int has = 0;
    for (int t = t0; t < t0 + 64; t++) {
        float val = values[base + (size_t)t * NV];
        float m = masks[base + (size_t)t * NV];
        float nv = (val - mn) / mm;
        if (m != 0.f) { last = nv; has = 1; }
        if (tc == 0 && t == 0) nv0s[v] = nv;
    }
    lastv[tc][v] = last; hasf[tc][v] = has;
    __syncthreads();
    float xp = nv0s[v];
    for (int q = tc - 1; q >= 0; q--) {
        if (hasf[q][v]) { xp = lastv[q][v]; break; }
    }
    for (int t = t0; t < t0 + 64; t++) {
        size_t i = base + (size_t)t * NV;
        float val = values[i], m = masks[i], d = deltas[i];
        float nv = (val - mn) / mm;
        float g = expf(-fmaxf(fmaf(d, wd, bdv), 0.0f));
        float xd = g * xp + (1.0f - g) * nmean;
        float xc = m * nv + (1.0f - m) * xd;
        xcomp[i] = xc; gam[i] = g;
        xp = (m != 0.f) ? nv : xp;
    }
}

// ---------------- K_gates: MFMA GEMM for input-side gate projections ----------------
__global__ __launch_bounds__(256) void k_gates(
    const float* __restrict__ xcomp, const float* __restrict__ masks,
    const unsigned short* __restrict__ wgf, const unsigned short* __restrict__ wgb,
    const unsigned short* __restrict__ wgg, const float* __restrict__ bihg,
    float* __restrict__ gf, float* __restrict__ gb, float* __restrict__ gg) {
    int wave = threadIdx.x >> 6, lane = threadIdx.x & 63;
    int bt0 = blockIdx.x * 64 + wave * 16;
    int r = lane & 15, kc = lane >> 4;
    const float* xr = xcomp + (size_t)(bt0 + r) * NV + kc * 8;
    const float* mr = masks + (size_t)(bt0 + r) * NV + kc * 8;
    short8 af0 = pack8(*(const float4*)(xr), *(const float4*)(xr + 4));
    short8 af1 = pack8(*(const float4*)(xr + 32), *(const float4*)(xr + 36));
    short8 af2 = pack8(*(const float4*)(mr), *(const float4*)(mr + 4));
    short8 af3 = pack8(*(const float4*)(mr + 32), *(const float4*)(mr + 36));
    #pragma unroll 4
    for (int nt = 0; nt < 16; nt++) {
        const unsigned short* w = wgf + (size_t)(nt * 16 + r) * 128 + kc * 8;
        f32x4 acc = {0.f, 0.f, 0.f, 0.f};
        acc = __builtin_amdgcn_mfma_f32_16x16x32_bf16(af0, *(const short8*)(w), acc, 0, 0, 0);
        acc = __builtin_amdgcn_mfma_f32_16x16x32_bf16(af1, *(const short8*)(w + 32), acc, 0, 0, 0);
        acc = __builtin_amdgcn_mfma_f32_16x16x32_bf16(af2, *(const short8*)(w + 64), acc, 0, 0, 0);
        acc = __builtin_amdgcn_mfma_f32_16x16x32_bf16(af3, *(const short8*)(w + 96), acc, 0, 0, 0);
        int col = nt * 16 + r, g = col >> 6, n = col & 63;
        #pragma unroll
        for (int i = 0; i < 4; i++)
            gf[((size_t)(bt0 + kc * 4 + i) * 64 + n) * 4 + g] = acc[i];
    }
    #pragma unroll 4
    for (int nt = 0; nt < 16; nt++) {
        const unsigned short* w = wgb + (size_t)(nt * 16 + r) * 128 + kc * 8;
        f32x4 acc = {0.f, 0.f, 0.f, 0.f};
        acc = __builtin_amdgcn_mfma_f32_16x16x32_bf16(af0, *(const short8*)(w), acc, 0, 0, 0);
        acc = __builtin_amdgcn_mfma_f32_16x16x32_bf16(af1, *(const short8*)(w + 32), acc, 0, 0, 0);
        acc = __builtin_amdgcn_mfma_f32_16x16x32_bf16(af2, *(const short8*)(w + 64), acc, 0, 0, 0);
        acc = __builtin_amdgcn_mfma_f32_16x16x32_bf16(af3, *(const short8*)(w + 96), acc, 0, 0, 0);
        int col = nt * 16 + r, g = col >> 6, n = col & 63;
        #pragma unroll
        for (int i = 0; i < 4; i++)
            gb[((size_t)(bt0 + kc * 4 + i) * 64 + n) * 4 + g] = acc[i];
    }
    #pragma unroll 3
    for (int nt = 0; nt < 6; nt++) {
        const unsigned short* w = wgg + (size_t)(nt * 16 + r) * 128 + kc * 8;
        float bias = bihg[nt * 16 + r];
        f32x4 acc = {bias, bias, bias, bias};
        acc = __builtin_amdgcn_mfma_f32_16x16x32_bf16(af0, *(const short8*)(w), acc, 0, 0, 0);
        acc = __builtin_amdgcn_mfma_f32_16x16x32_bf16(af1, *(const short8*)(w + 32), acc, 0, 0, 0);
        acc = __builtin_amdgcn_mfma_f32_16x16x32_bf16(af2, *(const short8*)(w + 64), acc, 0, 0, 0);
        acc = __builtin_amdgcn_mfma_f32_16x16x32_bf16(af3, *(const short8*)(w + 96), acc, 0, 0, 0);
        #pragma unroll
        for (int i = 0; i < 4; i++)
            gg[(size_t)(bt0 + kc * 4 + i) * 96 + nt * 16 + r] = acc[i];
    }
}

// ---------------- K3: ctx MLP ----------------
__global__ void k_ctxmlp(const float* __restrict__ stats, const float* __restrict__ Wc1,
                         const float* __restrict__ bc1, const float* __restrict__ Wc2,
                         const float* __restrict__ bc2, float* __restrict__ ctx) {
    int b = blockIdx.x, tid = threadIdx.x;  // 64 threads
    __shared__ float lw[64 * 193];
    __shared__ float ss[193];
    __shared__ float h1[64];
    for (int i = tid; i < 64 * 193; i += 64) lw[i] = Wc1[i];
    ss[tid] = stats[b * 256 + tid];
    ss[64 + tid] = stats[b * 256 + 64 + tid];
    ss[128 + tid] = stats[b * 256 + 128 + tid];
    if (tid == 0) ss[192] = stats[b * 256 + 192];
    __syncthreads();
    float acc = bc1[tid];
    const float* w = lw + tid * 193;
    for (int k = 0; k < 193; k++) acc = fmaf(w[k], ss[k], acc);
    h1[tid] = fmaxf(acc, 0.f);
    __syncthreads();
    if (tid < 32) {
        float a = bc2[tid];
        const float* w2 = Wc2 + tid * 64;
        for (int k = 0; k < 64; k++) a = fmaf(w2[k], h1[k], a);
        ctx[b * 64 + tid] = a;
    }
}

// ---------------- K4: GRU — 1 wave = 2 samples, f16 weights in VGPRs + fdot2 ----------------
__global__ __launch_bounds__(64, 1) void k_gru(
    const float* __restrict__ gg_t, const int* __restrict__ lengths,
    const unsigned short* __restrict__ whhg_h, const float* __restrict__ bhh,
    float* __restrict__ ctx) {
    int b0 = blockIdx.x * 2;
    int lane = threadIdx.x;
    int s = lane >> 5, n = lane & 31;
    int b = b0 + s;
    __shared__ __align__(16) unsigned short hs[2][32];
    WU w[3][4];
    float bh[3];
    #pragma unroll
    for (int g = 0; g < 3; g++) {
        #pragma unroll
        for (int q = 0; q < 4; q++)
            w[g][q].f4 = *(const fvec4*)(whhg_h + (size_t)(g * 32 + n) * 32 + q * 8);
        bh[g] = bhh[g * 32 + n];
    }
    int len = lengths[b];
    float hprev = 0.f, hn = 0.f;
    hs[s][n] = f2h(0.f);
    const float* gbase = gg_t + (size_t)b * NT * 96;
    float gc0 = gbase[n], gc1 = gbase[32 + n], gc2 = gbase[64 + n];
    __syncthreads();
    for (int t = 0; t < NT; t++) {
        WU hh[4];
        const fvec4* hp = (const fvec4*)hs[s];
        #pragma unroll
        for (int q = 0; q < 4; q++) hh[q].f4 = hp[q];
        float dr = 0.f, dz = 0.f, dn = 0.f;
        #pragma unroll
        for (int q = 0; q < 4; q++) {
            #pragma unroll
            for (int j = 0; j < 4; j++) {
                f16x2 hv2 = hh[q].h[j];
                dr = dot2acc(w[0][q].h[j], hv2, dr);
                dz = dot2acc(w[1][q].h[j], hv2, dz);
                dn = dot2acc(w[2][q].h[j], hv2, dn);
            }
        }
        float gn0 = 0.f, gn1 = 0.f, gn2 = 0.f;
        if (t + 1 < NT) {
            const float* gt = gbase + (size_t)(t + 1) * 96;
            gn0 = gt[n]; gn1 = gt[32 + n]; gn2 = gt[64 + n];
        }
        float rr = fsigm(gc0 + bh[0] + dr);
        float zz = fsigm(gc1 + bh[1] + dz);
        float nn = ftanh(gc2 + rr * (bh[2] + dn));
        float h = (1.f - zz) * nn + zz * hprev;
        hprev = h;
        if (t < len) hn = h;
        __syncthreads();
        hs[s][n] = f2h(h);
        __syncthreads();
        gc0 = gn0; gc1 = gn1; gc2 = gn2;
    }
    ctx[b * 64 + 32 + n] = hn;
}

// ---------------- K5: hinit ----------------
__global__ void k_hinit(const float* __restrict__ ctx, const float* __restrict__ Wi,
                        const float* __restrict__ bi, float* __restrict__ hinit) {
    int b = blockIdx.x; int j = threadIdx.x;  // 128
    __shared__ __align__(16) float sc[64];
    if (j < 64) sc[j] = ctx[b * 64 + j];
    __syncthreads();
    const float4* w = (const float4*)(Wi + (size_t)j * 64);
    const float4* c4 = (const float4*)sc;
    float4 a = {0, 0, 0, 0};
    #pragma unroll
    for (int q = 0; q < 16; q++) dot4(a, w[q], c4[q]);
    hinit[b * 128 + j] = bi[j] + a.x + a.y + a.z + a.w;
}

// ---------------- K_cterm: ctx-part of LSTM gates + biases, [dir*128+b][64][4] ----------------
__global__ void k_cterm(const float* __restrict__ ctx,
                        const float* __restrict__ Wihf, const float* __restrict__ Wihb,
                        const float* __restrict__ bihf, const float* __restrict__ bhhf,
                        const float* __restrict__ bihb, const float* __restrict__ bhhb,
                        float* __restrict__ ct_out) {
    int bx = blockIdx.x; int dir = bx >> 7; int b = bx & 127;
    int col = threadIdx.x;  // 256
    __shared__ __align__(16) float sc[64];
    if (col < 64) sc[col] = ctx[b * 64 + col];
    __syncthreads();
    const float* wc = (dir ? Wihb : Wihf) + (size_t)col * 192 + 128;
    float bias = dir ? (bihb[col] + bhhb[col]) : (bihf[col] + bhhf[col]);
    const float4* c4 = (const float4*)sc;
    float4 a = {0, 0, 0, 0};
    #pragma unroll
    for (int q = 0; q < 16; q++) dot4(a, *(const float4*)(wc + q * 4), c4[q]);
    int g = col >> 6, n = col & 63;
    ct_out[((size_t)bx * 64 + n) * 4 + g] = bias + a.x + a.y + a.z + a.w;
}

// ---------------- K6: LSTM — 1 wave = 1 (sample,dir), f16 Whh in VGPRs + fdot2 ----------------
__global__ __launch_bounds__(64, 1) void k_lstm(
    const float* __restrict__ gf, const float* __restrict__ gb,
    const float* __restrict__ cterm, const float* __restrict__ hinit,
    const unsigned short* __restrict__ whhf_h, const unsigned short* __restrict__ whhb_h,
    float* __restrict__ out0, float* __restrict__ out1) {
    int bx = blockIdx.x; int dir = bx >> 7; int b = bx & 127;
    int n = threadIdx.x;  // 64
    const float* gates = dir ? gb : gf;
    const unsigned short* wsrc = dir ? whhb_h : whhf_h;
    float* hall = dir ? out1 : out0;
    __shared__ __align__(16) unsigned short hs[64];
    WU w[4][8];
    #pragma unroll
    for (int g = 0; g < 4; g++) {
        #pragma unroll
        for (int q = 0; q < 8; q++)
            w[g][q].f4 = *(const fvec4*)(wsrc + (size_t)(g * 64 + n) * 64 + q * 8);
    }
    float4 ctg = *(const float4*)(cterm + ((size_t)bx * 64 + n) * 4);
    float c;
    {
        float h0 = hinit[b * 128 + dir * 64 + n];
        c = ftanh(h0);
        hs[n] = f2h(h0);
        int t0 = dir ? (NT - 1) : 0;
        hall[((size_t)b * NT + t0) * NV + n] = h0;
    }
    size_t gbase = (size_t)b * NT * 256;  // [t][64][4]
    int tin0 = dir ? (NT - 1) : 0;
    float4 gc = *(const float4*)(gates + gbase + (size_t)tin0 * 256 + n * 4);
    __syncthreads();
    for (int s = 0; s < NT - 1; s++) {
        WU hh[8];
        const fvec4* hp = (const fvec4*)hs;
        #pragma unroll
        for (int q = 0; q < 8; q++) hh[q].f4 = hp[q];
        float di = 0.f, df = 0.f, dg = 0.f, dq = 0.f;
        #pragma unroll
        for (int q = 0; q < 8; q++) {
            #pragma unroll
            for (int j = 0; j < 4; j++) {
                f16x2 hv2 = hh[q].h[j];
                di = dot2acc(w[0][q].h[j], hv2, di);
                df = dot2acc(w[1][q].h[j], hv2, df);
                dg = dot2acc(w[2][q].h[j], hv2, dg);
                dq = dot2acc(w[3][q].h[j], hv2, dq);
            }
        }
        int tnext = dir ? (NT - 2 - s) : (s + 1);
        float4 gn = *(const float4*)(gates + gbase + (size_t)tnext * 256 + n * 4);
        float ii = fsigm(gc.x + ctg.x + di);
        float ff = fsigm(gc.y + ctg.y + df);
        float gv = ftanh(gc.z + ctg.z + dg);
        float oo = fsigm(gc.w + ctg.w + dq);
        c = ff * c + ii * gv;
        float hv = oo * ftanh(c);
        int tout = dir ? (NT - 2 - s) : (s + 1);
        hall[((size_t)b * NT + tout) * NV + n] = hv;
        __syncthreads();
        hs[n] = f2h(hv);
        __syncthreads();
        gc = gn;
    }
}

// ---------------- K_feat: fused per-feature MLP via bf16 MFMA ----------------
__global__ __launch_bounds__(256) void k_feat(
    const float* __restrict__ xcomp, const unsigned short* __restrict__ wbf,
    const float* __restrict__ wdiag, const float* __restrict__ bfeat,
    const float* __restrict__ Wnl1, const float* __restrict__ bnl1,
    const float* __restrict__ Wnl2, const float* __restrict__ bnl2,
    float* __restrict__ feat_out) {
    int wave = threadIdx.x >> 6; int lane = threadIdx.x & 63;
    int bt0 = blockIdx.x * 64 + wave * 16;
    int r = lane & 15, kc = lane >> 4;
    __shared__ __align__(16) unsigned short hb[4][16 * 32];
    __shared__ __align__(16) float ldsx[4][64 * 16];
    __shared__ __align__(16) float fl[4][16 * 65];
    unsigned short* hbw = hb[wave];
    float* lx = ldsx[wave];
    float* flw = fl[wave];

    short8 a0, a1;
    {
        const float* xr = xcomp + (size_t)(bt0 + r) * NV + kc * 8;
        a0 = pack8(*(const float4*)(xr), *(const float4*)(xr + 4));
        a1 = pack8(*(const float4*)(xr + 32), *(const float4*)(xr + 36));
    }
    {
        int gc0 = kc * 16;
        const float* xr2 = xcomp + (size_t)(bt0 + r) * NV + gc0;
        #pragma unroll
        for (int e = 0; e < 16; e += 4) {
            float4 p = *(const float4*)(xr2 + e);
            lx[(gc0 + e + 0) * 16 + r] = bf2f(f2bf(p.x));
            lx[(gc0 + e + 1) * 16 + r] = bf2f(f2bf(p.y));
            lx[(gc0 + e + 2) * 16 + r] = bf2f(f2bf(p.z));
            lx[(gc0 + e + 3) * 16 + r] = bf2f(f2bf(p.w));
        }
    }
    short8 wb0, wb1;
    {
        const float* w = Wnl1 + r * 32 + kc * 8;
        wb0 = pack8(*(const float4*)w, *(const float4*)(w + 4));
        const float* w2 = Wnl1 + (16 + r) * 32 + kc * 8;
        wb1 = pack8(*(const float4*)w2, *(const float4*)(w2 + 4));
    }
    float w2c0 = Wnl2[r], w2c1 = Wnl2[16 + r];
    float bn0 = bnl1[r], bn1 = bnl1[16 + r];
    float bn2 = bnl2[0];
    __builtin_amdgcn_wave_barrier();

    #pragma unroll 2
    for (int g = 0; g < 64; g++) {
        __builtin_amdgcn_wave_barrier();
        float xv[4];
        #pragma unroll
        for (int i = 0; i < 4; i++) xv[i] = lx[g * 16 + kc * 4 + i];
        float p[4] = {0.f, 0.f, 0.f, 0.f};
        #pragma unroll
        for (int f = 0; f < 2; f++) {
            int n0 = g * 32 + f * 16;
            const unsigned short* wrow = wbf + (size_t)(n0 + r) * 64;
            short8 b0 = *(const short8*)(wrow + kc * 8);
            short8 b1 = *(const short8*)(wrow + 32 + kc * 8);
            f32x4 acc = {0.f, 0.f, 0.f, 0.f};
            acc = __builtin_amdgcn_mfma_f32_16x16x32_bf16(a0, b0, acc, 0, 0, 0);
            acc = __builtin_amdgcn_mfma_f32_16x16x32_bf16(a1, b1, acc, 0, 0, 0);
            int n = n0 + r;
            float wd = wdiag[n], bs = bfeat[n];
            #pragma unroll
            for (int i = 0; i < 4; i++) {
                float h = acc[i] - xv[i] * wd + bs;
                h = fmaxf(h, 0.0f);
                hbw[(kc * 4 + i) * 32 + f * 16 + r] = f2bf(h);
            }
        }
        __builtin_amdgcn_wave_barrier();
        short8 ah = *(const short8*)(hbw + r * 32 + kc * 8);
        f32x4 z0 = {0.f, 0.f, 0.f, 0.f}, z1 = {0.f, 0.f, 0.f, 0.f};
        z0 = __builtin_amdgcn_mfma_f32_16x16x32_bf16(ah, wb0, z0, 0, 0, 0);
        z1 = __builtin_amdgcn_mfma_f32_16x16x32_bf16(ah, wb1, z1, 0, 0, 0);
        #pragma unroll
        for (int i = 0; i < 4; i++) {
            float za = fmaxf(z0[i] + bn0, 0.0f);
            float zb = fmaxf(z1[i] + bn1, 0.0f);
            p[i] = fmaf(za, w2c0, fmaf(zb, w2c1, p[i]));
        }
        #pragma unroll
        for (int m = 1; m < 16; m <<= 1) {
            #pragma unroll
            for (int i = 0; i < 4; i++) p[i] += __shfl_xor(p[i], m, 64);
        }
        if (r == 0) {
            #pragma unroll
            for (int i = 0; i < 4; i++) flw[(kc * 4 + i) * 65 + g] = p[i] + bn2;
        }
    }
    __builtin_amdgcn_wave_barrier();
    #pragma unroll
    for (int q = 0; q < 16; q++)
        feat_out[(size_t)(bt0 + q) * NV + lane] = flw[q * 65 + lane];
}

// ---------------- K7: rnn_imp = h_cat @ W_ri^T + b_ri ----------------
__global__ void k_rnnimp(const float* __restrict__ out0, const float* __restrict__ out1,
                         const float* __restrict__ Wri, const float* __restrict__ bri,
                         float* __restrict__ rnnraw) {
    int bt0 = blockIdx.x * 4;
    int tid = threadIdx.x;
    int rr = tid >> 6, v = tid & 63;
    __shared__ __align__(16) float hc[4][128];
    hc[rr][v] = out0[(size_t)(bt0 + rr) * NV + v];
    hc[rr][64 + v] = out1[(size_t)(bt0 + rr) * NV + v];
    __syncthreads();
    const float4* w = (const float4*)(Wri + (size_t)v * 128);
    const float4* h4 = (const float4*)hc[rr];
    float4 a = {0, 0, 0, 0};
    #pragma unroll
    for (int q = 0; q < 32; q++) dot4(a, w[q], h4[q]);
    rnnraw[(size_t)(bt0 + rr) * NV + v] = bri[v] + a.x + a.y + a.z + a.w;
}

// ---------------- K8: beta fusion + scale + write all 3 outputs ----------------
__global__ void k_final(const float* __restrict__ rnnraw, const float* __restrict__ gam,
                        const float* __restrict__ masks, const float* __restrict__ Wfu,
                        const float* __restrict__ bfu, const float* __restrict__ mmn_ws,
                        const float* __restrict__ minv, float* __restrict__ out0,
                        float* __restrict__ out1, float* __restrict__ out2) {
    int bt0 = blockIdx.x * 4; int tid = threadIdx.x;
    int rr = tid >> 6, v = tid & 63;
    __shared__ __align__(16) float gm[4][128];
    size_t row = (size_t)(bt0 + rr) * NV;
    gm[rr][v] = gam[row + v];
    gm[rr][64 + v] = masks[row + v];
    __syncthreads();
    const float4* w = (const float4*)(Wfu + (size_t)v * 128);
    const float4* x4 = (const float4*)gm[rr];
    float4 a = {0, 0, 0, 0};
    #pragma unroll
    for (int q = 0; q < 32; q++) dot4(a, w[q], x4[q]);
    float beta = sigm(bfu[v] + a.x + a.y + a.z + a.w);
    size_t idx = row + v;
    float rn = rnnraw[idx];
    float ft = out2[idx];
    float fin = beta * ft + (1.0f - beta) * rn;
    int b = (bt0 + rr) >> 8;
    float mm = mmn_ws[b * NV + v], mn = minv[b * NV + v];
    out0[idx] = fmaf(rn, mm, mn);
    out1[idx] = fmaf(ft, mm, mn);
    out2[idx] = fmaf(fin, mm, mn);
}

extern "C" void kernel_launch(void* const* d_in, const int* in_sizes, int n_in,
                              void* d_out, int out_size, void* d_ws, size_t ws_size,
                              hipStream_t stream) {
    const int*   lengths  = (const int*)d_in[0];
    const float* values   = (const float*)d_in[1];
    const float* masks    = (const float*)d_in[2];
    const float* deltas   = (const float*)d_in[3];
    const float* min_vals = (const float*)d_in[4];
    const float* max_vals = (const float*)d_in[5];
    const float* W_decay  = (const float*)d_in[6];
    const float* b_decay  = (const float*)d_in[7];
    const float* W_feat   = (const float*)d_in[8];
    const float* b_feat   = (const float*)d_in[9];
    const float* W_nl1    = (const float*)d_in[10];
    const float* b_nl1    = (const float*)d_in[11];
    const float* W_nl2    = (const float*)d_in[12];
    const float* b_nl2    = (const float*)d_in[13];
    const float* Wc1      = (const float*)d_in[14];
    const float* bc1      = (const float*)d_in[15];
    const float* Wc2      = (const float*)d_in[16];
    const float* bc2      = (const float*)d_in[17];
    const float* W_ih_g   = (const float*)d_in[18];
    const float* W_hh_g   = (const float*)d_in[19];
    const float* b_ih_g   = (const float*)d_in[20];
    const float* b_hh_g   = (const float*)d_in[21];
    const float* W_init   = (const float*)d_in[22];
    const float* b_init   = (const float*)d_in[23];
    const float* W_ih_f   = (const float*)d_in[24];
    const float* W_hh_f   = (const float*)d_in[25];
    const float* b_ih_f   = (const float*)d_in[26];
    const float* b_hh_f   = (const float*)d_in[27];
    const float* W_ih_b   = (const float*)d_in[28];
    const float* W_hh_b   = (const float*)d_in[29];
    const float* b_ih_b   = (const float*)d_in[30];
    const float* b_hh_b   = (const float*)d_in[31];
    const float* W_ri     = (const float*)d_in[32];
    const float* b_ri     = (const float*)d_in[33];
    const float* W_fu     = (const float*)d_in[34];
    const float* b_fu     = (const float*)d_in[35];

    float* ws = (float*)d_ws;
    float* xcomp  = ws;                     // 2097152
    float* gam    = ws + 2097152;           // 2097152
    float* rnnraw = ws + 4194304;           // 2097152
    float* stats  = ws + 6291456;           // 32768
    float* mmn    = ws + 6324224;           // 8192
    float* nmeans = ws + 6332416;           // 8192
    float* ctx    = ws + 6340608;           // 8192
    float* hinit  = ws + 6348800;           // 16384
    unsigned short* wbf = (unsigned short*)(ws + 6365184);  // 131072 u16
    float* wdiag  = ws + 6430720;           // 2048
    unsigned short* wgf = (unsigned short*)(ws + 6432768);  // 32768 u16
    unsigned short* wgb = (unsigned short*)(ws + 6449152);  // 32768 u16
    unsigned short* wgg = (unsigned short*)(ws + 6465536);  // 12288 u16
    unsigned short* whhf_h = (unsigned short*)(ws + 6471680); // 16384 u16
    unsigned short* whhb_h = (unsigned short*)(ws + 6479872); // 16384 u16
    unsigned short* whhg_h = (unsigned short*)(ws + 6488064); // 3072 u16
    float* cterm  = ws + 6489600;           // 65536
    float* gates_f = ws + 6555136;          // 8388608
    float* gates_b = ws + 14943744;         // 8388608
    float* gates_g = ws + 23332352;         // 3145728  (end ≈ 106 MB)

    float* out0 = (float*)d_out;
    float* out1 = out0 + NBTV;
    float* out2 = out0 + 2 * NBTV;

    k_conv<<<512, 256, 0, stream>>>(W_feat, W_ih_f, W_ih_b, W_ih_g, W_hh_f, W_hh_b, W_hh_g,
                                    wbf, wdiag, wgf, wgb, wgg, whhf_h, whhb_h, whhg_h);
    k_stats<<<NB, 256, 0, stream>>>(lengths, values, masks, min_vals, max_vals, stats, mmn, nmeans);
    k_fill<<<NB, 256, 0, stream>>>(values, masks, deltas, min_vals, W_decay, b_decay, mmn, nmeans, xcomp, gam);
    k_gates<<<NBT / 64, 256, 0, stream>>>(xcomp, masks, wgf, wgb, wgg, b_ih_g, gates_f, gates_b, gates_g);
    k_feat<<<NBT / 64, 256, 0, stream>>>(xcomp, wbf, wdiag, b_feat, W_nl1, b_nl1, W_nl2, b_nl2, out2);
    k_ctxmlp<<<NB, 64, 0, stream>>>(stats, Wc1, bc1, Wc2, bc2, ctx);
    k_gru<<<64, 64, 0, stream>>>(gates_g, lengths, whhg_h, b_hh_g, ctx);
    k_hinit<<<NB, 128, 0, stream>>>(ctx, W_init, b_init, hinit);
    k_cterm<<<256, 256, 0, stream>>>(ctx, W_ih_f, W_ih_b, b_ih_f, b_hh_f, b_ih_b, b_hh_b, cterm);
    k_lstm<<<256, 64, 0, stream>>>(gates_f, gates_b, cterm, hinit, whhf_h, whhb_h, out0, out1);
    k_rnnimp<<<NBT / 4, 256, 0, stream>>>(out0, out1, W_ri, b_ri, rnnraw);
    k_final<<<NBT / 4, 256, 0, stream>>>(rnnraw, gam, masks, W_fu, b_fu, mmn, min_vals, out0, out1, out2);
}

// Round 7
// 441.925 us; speedup vs baseline: 2.0563x; 1.4799x over previous
//
#include <hip/hip_runtime.h>

static constexpr int NB = 128;
static constexpr int NT = 256;
static constexpr int NV = 64;
static constexpr int NBT = NB * NT;       // 32768
static constexpr int NBTV = NBT * NV;     // 2097152

typedef __attribute__((ext_vector_type(8))) short short8;
typedef __attribute__((ext_vector_type(4))) float f32x4;
typedef __attribute__((ext_vector_type(4))) float fvec4;
typedef __attribute__((ext_vector_type(2))) _Float16 f16x2;

union WU { fvec4 f4; f16x2 h[4]; };

#if defined(__has_builtin)
#if __has_builtin(__builtin_amdgcn_fdot2)
#define HAS_FDOT2 1
#endif
#endif

__device__ __forceinline__ float dot2acc(f16x2 a, f16x2 b, float c) {
#ifdef HAS_FDOT2
    return __builtin_amdgcn_fdot2(a, b, c, false);
#else
    return c + (float)a[0] * (float)b[0] + (float)a[1] * (float)b[1];
#endif
}

__device__ __forceinline__ unsigned short f2bf(float x) {
    unsigned int u = __float_as_uint(x);
    return (unsigned short)((u + 0x7FFFu + ((u >> 16) & 1u)) >> 16);
}
__device__ __forceinline__ float bf2f(unsigned short b) {
    return __uint_as_float(((unsigned int)b) << 16);
}
__device__ __forceinline__ unsigned short f2h(float x) {
    union { _Float16 h; unsigned short u; } c; c.h = (_Float16)x; return c.u;
}
__device__ __forceinline__ float sigm(float x) { return 1.0f / (1.0f + expf(-x)); }
__device__ __forceinline__ float fsigm(float x) {
    return __builtin_amdgcn_rcpf(1.0f + __expf(-x));
}
__device__ __forceinline__ float ftanh(float x) {
    return 1.0f - 2.0f * __builtin_amdgcn_rcpf(1.0f + __expf(2.0f * x));
}

__device__ __forceinline__ short8 pack8(float4 a, float4 b) {
    short8 r;
    r[0] = (short)f2bf(a.x); r[1] = (short)f2bf(a.y); r[2] = (short)f2bf(a.z); r[3] = (short)f2bf(a.w);
    r[4] = (short)f2bf(b.x); r[5] = (short)f2bf(b.y); r[6] = (short)f2bf(b.z); r[7] = (short)f2bf(b.w);
    return r;
}

__device__ __forceinline__ void dot4(float4& acc, const float4 wv, const float4 xv) {
    acc.x = fmaf(wv.x, xv.x, acc.x);
    acc.y = fmaf(wv.y, xv.y, acc.y);
    acc.z = fmaf(wv.z, xv.z, acc.z);
    acc.w = fmaf(wv.w, xv.w, acc.w);
}

// ---------------- K0: weight conversions ----------------
__global__ void k_conv(const float* __restrict__ Wf, const float* __restrict__ Wihf,
                       const float* __restrict__ Wihb, const float* __restrict__ Wihg,
                       const float* __restrict__ Whhf, const float* __restrict__ Whhb,
                       const float* __restrict__ Whhg, const float* __restrict__ Wri,
                       const float* __restrict__ Wfu,
                       unsigned short* __restrict__ wbf, float* __restrict__ wdiag,
                       unsigned short* __restrict__ wgf, unsigned short* __restrict__ wgb,
                       unsigned short* __restrict__ wgg,
                       unsigned short* __restrict__ whhf_h, unsigned short* __restrict__ whhb_h,
                       unsigned short* __restrict__ whhg_h,
                       unsigned short* __restrict__ wri_bf, unsigned short* __restrict__ wfu_bf) {
    int i = blockIdx.x * 256 + threadIdx.x;
    if (i < NV * 32 * NV) wbf[i] = f2bf(Wf[i]);
    if (i < 2048) wdiag[i] = bf2f(f2bf(Wf[i * 64 + (i >> 5)]));
    if (i < 32768) {
        int n = i >> 7, k = i & 127;
        wgf[i] = f2bf(Wihf[n * 192 + k]);
        wgb[i] = f2bf(Wihb[n * 192 + k]);
    }
    if (i < 12288) wgg[i] = f2bf(Wihg[i]);
    if (i < 16384) { whhf_h[i] = f2h(Whhf[i]); whhb_h[i] = f2h(Whhb[i]); }
    if (i < 3072) whhg_h[i] = f2h(Whhg[i]);
    if (i < 8192) { wri_bf[i] = f2bf(Wri[i]); wfu_bf[i] = f2bf(Wfu[i]); }
}

// ---------------- K1: per-(b,v) stats (4-way t-split) ----------------
__global__ __launch_bounds__(256) void k_stats(
    const int* __restrict__ lengths, const float* __restrict__ values,
    const float* __restrict__ masks, const float* __restrict__ minv,
    const float* __restrict__ maxv, float* __restrict__ stats,
    float* __restrict__ mmn_ws, float* __restrict__ nmeans_ws) {
    int b = blockIdx.x; int tid = threadIdx.x;
    int v = tid & 63; int tc = tid >> 6;
    const float* vp = values + (size_t)b * NT * NV;
    const float* mp = masks + (size_t)b * NT * NV;
    float sv = 0.f, sq = 0.f, sm = 0.f;
    for (int t = tc; t < NT; t += 4) {
        float x = vp[t * NV + v]; float m = mp[t * NV + v];
        sv += x; sq += x * x; sm += m;
    }
    __shared__ float red[3][4][64];
    red[0][tc][v] = sv; red[1][tc][v] = sq; red[2][tc][v] = sm;
    __syncthreads();
    if (tc == 0) {
        sv = red[0][0][v] + red[0][1][v] + red[0][2][v] + red[0][3][v];
        sq = red[1][0][v] + red[1][1][v] + red[1][2][v] + red[1][3][v];
        sm = red[2][0][v] + red[2][1][v] + red[2][2][v] + red[2][3][v];
        float mean = sv / sm;
        float var = (sq - 2.0f * mean * sv + (float)NT * mean * mean) / (sm - 1.0f);
        var = fmaxf(var, 0.0f);
        float sd = sqrtf(var);
        float lf = (float)lengths[b];
        float miss = 1.0f - sm / lf;
        float mn = minv[b * NV + v]; float mx = maxv[b * NV + v];
        float mm = fmaxf(mx - mn, 1e-8f);
        float* st = stats + b * 256;
        if (v == 0) st[0] = lf;
        st[1 + v] = mean; st[65 + v] = sd; st[129 + v] = miss;
        mmn_ws[b * NV + v] = mm;
        nmeans_ws[b * NV + v] = (mean - mn) / mm;
    }
}

// ---------------- K2: forward-fill (chunked scan) + decay + x_complete ----------------
__global__ __launch_bounds__(256) void k_fill(
    const float* __restrict__ values, const float* __restrict__ masks,
    const float* __restrict__ deltas, const float* __restrict__ minv,
    const float* __restrict__ Wd, const float* __restrict__ bd,
    const float* __restrict__ mmn_ws, const float* __restrict__ nmeans_ws,
    float* __restrict__ xcomp, float* __restrict__ gam) {
    int b = blockIdx.x; int tid = threadIdx.x;
    int v = tid & 63; int tc = tid >> 6;
    float mn = minv[b * NV + v];
    float mm = mmn_ws[b * NV + v];
    float nmean = nmeans_ws[b * NV + v];
    float wd = Wd[v * NV + v], bdv = bd[v];
    size_t base = (size_t)b * NT * NV + v;
    __shared__ float lastv[4][64];
    __shared__ int hasf[4][64];
    __shared__ float nv0s[64];
    int t0 = tc * 64;
    float last = 0.f; int has = 0;
    for (int t = t0; t < t0 + 64; t++) {
        float val = values[base + (size_t)t * NV];
        float m = masks[base + (size_t)t * NV];
        float nv = (val - mn) / mm;
        if (m != 0.f) { last = nv; has = 1; }
        if (tc == 0 && t == 0) nv0s[v] = nv;
    }
    lastv[tc][v] = last; hasf[tc][v] = has;
    __syncthreads();
    float xp = nv0s[v];
    for (int q = tc - 1; q >= 0; q--) {
        if (hasf[q][v]) { xp = lastv[q][v]; break; }
    }
    for (int t = t0; t < t0 + 64; t++) {
        size_t i = base + (size_t)t * NV;
        float val = values[i], m = masks[i], d = deltas[i];
        float nv = (val - mn) / mm;
        float g = expf(-fmaxf(fmaf(d, wd, bdv), 0.0f));
        float xd = g * xp + (1.0f - g) * nmean;
        float xc = m * nv + (1.0f - m) * xd;
        xcomp[i] = xc; gam[i] = g;
        xp = (m != 0.f) ? nv : xp;
    }
}

// ---------------- K_gates: MFMA GEMM for input-side gate projections ----------------
__global__ __launch_bounds__(256) void k_gates(
    const float* __restrict__ xcomp, const float* __restrict__ masks,
    const unsigned short* __restrict__ wgf, const unsigned short* __restrict__ wgb,
    const unsigned short* __restrict__ wgg, const float* __restrict__ bihg,
    float* __restrict__ gf, float* __restrict__ gb, float* __restrict__ gg) {
    int wave = threadIdx.x >> 6, lane = threadIdx.x & 63;
    int bt0 = blockIdx.x * 64 + wave * 16;
    int r = lane & 15, kc = lane >> 4;
    const float* xr = xcomp + (size_t)(bt0 + r) * NV + kc * 8;
    const float* mr = masks + (size_t)(bt0 + r) * NV + kc * 8;
    short8 af0 = pack8(*(const float4*)(xr), *(const float4*)(xr + 4));
    short8 af1 = pack8(*(const float4*)(xr + 32), *(const float4*)(xr + 36));
    short8 af2 = pack8(*(const float4*)(mr), *(const float4*)(mr + 4));
    short8 af3 = pack8(*(const float4*)(mr + 32), *(const float4*)(mr + 36));
    #pragma unroll 4
    for (int nt = 0; nt < 16; nt++) {
        const unsigned short* w = wgf + (size_t)(nt * 16 + r) * 128 + kc * 8;
        f32x4 acc = {0.f, 0.f, 0.f, 0.f};
        acc = __builtin_amdgcn_mfma_f32_16x16x32_bf16(af0, *(const short8*)(w), acc, 0, 0, 0);
        acc = __builtin_amdgcn_mfma_f32_16x16x32_bf16(af1, *(const short8*)(w + 32), acc, 0, 0, 0);
        acc = __builtin_amdgcn_mfma_f32_16x16x32_bf16(af2, *(const short8*)(w + 64), acc, 0, 0, 0);
        acc = __builtin_amdgcn_mfma_f32_16x16x32_bf16(af3, *(const short8*)(w + 96), acc, 0, 0, 0);
        int col = nt * 16 + r, g = col >> 6, n = col & 63;
        #pragma unroll
        for (int i = 0; i < 4; i++)
            gf[((size_t)(bt0 + kc * 4 + i) * 64 + n) * 4 + g] = acc[i];
    }
    #pragma unroll 4
    for (int nt = 0; nt < 16; nt++) {
        const unsigned short* w = wgb + (size_t)(nt * 16 + r) * 128 + kc * 8;
        f32x4 acc = {0.f, 0.f, 0.f, 0.f};
        acc = __builtin_amdgcn_mfma_f32_16x16x32_bf16(af0, *(const short8*)(w), acc, 0, 0, 0);
        acc = __builtin_amdgcn_mfma_f32_16x16x32_bf16(af1, *(const short8*)(w + 32), acc, 0, 0, 0);
        acc = __builtin_amdgcn_mfma_f32_16x16x32_bf16(af2, *(const short8*)(w + 64), acc, 0, 0, 0);
        acc = __builtin_amdgcn_mfma_f32_16x16x32_bf16(af3, *(const short8*)(w + 96), acc, 0, 0, 0);
        int col = nt * 16 + r, g = col >> 6, n = col & 63;
        #pragma unroll
        for (int i = 0; i < 4; i++)
            gb[((size_t)(bt0 + kc * 4 + i) * 64 + n) * 4 + g] = acc[i];
    }
    #pragma unroll 3
    for (int nt = 0; nt < 6; nt++) {
        const unsigned short* w = wgg + (size_t)(nt * 16 + r) * 128 + kc * 8;
        float bias = bihg[nt * 16 + r];
        f32x4 acc = {bias, bias, bias, bias};
        acc = __builtin_amdgcn_mfma_f32_16x16x32_bf16(af0, *(const short8*)(w), acc, 0, 0, 0);
        acc = __builtin_amdgcn_mfma_f32_16x16x32_bf16(af1, *(const short8*)(w + 32), acc, 0, 0, 0);
        acc = __builtin_amdgcn_mfma_f32_16x16x32_bf16(af2, *(const short8*)(w + 64), acc, 0, 0, 0);
        acc = __builtin_amdgcn_mfma_f32_16x16x32_bf16(af3, *(const short8*)(w + 96), acc, 0, 0, 0);
        #pragma unroll
        for (int i = 0; i < 4; i++)
            gg[(size_t)(bt0 + kc * 4 + i) * 96 + nt * 16 + r] = acc[i];
    }
}

// ---------------- K3: ctx MLP ----------------
__global__ void k_ctxmlp(const float* __restrict__ stats, const float* __restrict__ Wc1,
                         const float* __restrict__ bc1, const float* __restrict__ Wc2,
                         const float* __restrict__ bc2, float* __restrict__ ctx) {
    int b = blockIdx.x, tid = threadIdx.x;  // 64 threads
    __shared__ float lw[64 * 193];
    __shared__ float ss[193];
    __shared__ float h1[64];
    for (int i = tid; i < 64 * 193; i += 64) lw[i] = Wc1[i];
    ss[tid] = stats[b * 256 + tid];
    ss[64 + tid] = stats[b * 256 + 64 + tid];
    ss[128 + tid] = stats[b * 256 + 128 + tid];
    if (tid == 0) ss[192] = stats[b * 256 + 192];
    __syncthreads();
    float acc = bc1[tid];
    const float* w = lw + tid * 193;
    for (int k = 0; k < 193; k++) acc = fmaf(w[k], ss[k], acc);
    h1[tid] = fmaxf(acc, 0.f);
    __syncthreads();
    if (tid < 32) {
        float a = bc2[tid];
        const float* w2 = Wc2 + tid * 64;
        for (int k = 0; k < 64; k++) a = fmaf(w2[k], h1[k], a);
        ctx[b * 64 + tid] = a;
    }
}

// ---------------- K4: GRU — 1 wave = 2 samples, f16 weights in VGPRs + fdot2 ----------------
__global__ __launch_bounds__(64, 1) void k_gru(
    const float* __restrict__ gg_t, const int* __restrict__ lengths,
    const unsigned short* __restrict__ whhg_h, const float* __restrict__ bhh,
    float* __restrict__ ctx) {
    int b0 = blockIdx.x * 2;
    int lane = threadIdx.x;
    int s = lane >> 5, n = lane & 31;
    int b = b0 + s;
    __shared__ __align__(16) unsigned short hs[2][32];
    WU w[3][4];
    float bh[3];
    #pragma unroll
    for (int g = 0; g < 3; g++) {
        #pragma unroll
        for (int q = 0; q < 4; q++)
            w[g][q].f4 = *(const fvec4*)(whhg_h + (size_t)(g * 32 + n) * 32 + q * 8);
        bh[g] = bhh[g * 32 + n];
    }
    int len = lengths[b];
    float hprev = 0.f, hn = 0.f;
    hs[s][n] = f2h(0.f);
    const float* gbase = gg_t + (size_t)b * NT * 96;
    float gc0 = gbase[n], gc1 = gbase[32 + n], gc2 = gbase[64 + n];
    __syncthreads();
    for (int t = 0; t < NT; t++) {
        WU hh[4];
        const fvec4* hp = (const fvec4*)hs[s];
        #pragma unroll
        for (int q = 0; q < 4; q++) hh[q].f4 = hp[q];
        float dr = 0.f, dz = 0.f, dn = 0.f;
        #pragma unroll
        for (int q = 0; q < 4; q++) {
            #pragma unroll
            for (int j = 0; j < 4; j++) {
                f16x2 hv2 = hh[q].h[j];
                dr = dot2acc(w[0][q].h[j], hv2, dr);
                dz = dot2acc(w[1][q].h[j], hv2, dz);
                dn = dot2acc(w[2][q].h[j], hv2, dn);
            }
        }
        float gn0 = 0.f, gn1 = 0.f, gn2 = 0.f;
        if (t + 1 < NT) {
            const float* gt = gbase + (size_t)(t + 1) * 96;
            gn0 = gt[n]; gn1 = gt[32 + n]; gn2 = gt[64 + n];
        }
        float rr = fsigm(gc0 + bh[0] + dr);
        float zz = fsigm(gc1 + bh[1] + dz);
        float nn = ftanh(gc2 + rr * (bh[2] + dn));
        float h = (1.f - zz) * nn + zz * hprev;
        hprev = h;
        if (t < len) hn = h;
        __syncthreads();
        hs[s][n] = f2h(h);
        __syncthreads();
        gc0 = gn0; gc1 = gn1; gc2 = gn2;
    }
    ctx[b * 64 + 32 + n] = hn;
}

// ---------------- K5: hinit ----------------
__global__ void k_hinit(const float* __restrict__ ctx, const float* __restrict__ Wi,
                        const float* __restrict__ bi, float* __restrict__ hinit) {
    int b = blockIdx.x; int j = threadIdx.x;  // 128
    __shared__ __align__(16) float sc[64];
    if (j < 64) sc[j] = ctx[b * 64 + j];
    __syncthreads();
    const float4* w = (const float4*)(Wi + (size_t)j * 64);
    const float4* c4 = (const float4*)sc;
    float4 a = {0, 0, 0, 0};
    #pragma unroll
    for (int q = 0; q < 16; q++) dot4(a, w[q], c4[q]);
    hinit[b * 128 + j] = bi[j] + a.x + a.y + a.z + a.w;
}

// ---------------- K_cterm: ctx-part of LSTM gates + biases, [dir*128+b][64][4] ----------------
__global__ void k_cterm(const float* __restrict__ ctx,
                        const float* __restrict__ Wihf, const float* __restrict__ Wihb,
                        const float* __restrict__ bihf, const float* __restrict__ bhhf,
                        const float* __restrict__ bihb, const float* __restrict__ bhhb,
                        float* __restrict__ ct_out) {
    int bx = blockIdx.x; int dir = bx >> 7; int b = bx & 127;
    int col = threadIdx.x;  // 256
    __shared__ __align__(16) float sc[64];
    if (col < 64) sc[col] = ctx[b * 64 + col];
    __syncthreads();
    const float* wc = (dir ? Wihb : Wihf) + (size_t)col * 192 + 128;
    float bias = dir ? (bihb[col] + bhhb[col]) : (bihf[col] + bhhf[col]);
    const float4* c4 = (const float4*)sc;
    float4 a = {0, 0, 0, 0};
    #pragma unroll
    for (int q = 0; q < 16; q++) dot4(a, *(const float4*)(wc + q * 4), c4[q]);
    int g = col >> 6, n = col & 63;
    ct_out[((size_t)bx * 64 + n) * 4 + g] = bias + a.x + a.y + a.z + a.w;
}

// ---------------- K6: LSTM — 1 wave = 1 (sample,dir), f16 Whh in VGPRs + fdot2 ----------------
__global__ __launch_bounds__(64, 1) void k_lstm(
    const float* __restrict__ gf, const float* __restrict__ gb,
    const float* __restrict__ cterm, const float* __restrict__ hinit,
    const unsigned short* __restrict__ whhf_h, const unsigned short* __restrict__ whhb_h,
    float* __restrict__ out0, float* __restrict__ out1) {
    int bx = blockIdx.x; int dir = bx >> 7; int b = bx & 127;
    int n = threadIdx.x;  // 64
    const float* gates = dir ? gb : gf;
    const unsigned short* wsrc = dir ? whhb_h : whhf_h;
    float* hall = dir ? out1 : out0;
    __shared__ __align__(16) unsigned short hs[64];
    WU w[4][8];
    #pragma unroll
    for (int g = 0; g < 4; g++) {
        #pragma unroll
        for (int q = 0; q < 8; q++)
            w[g][q].f4 = *(const fvec4*)(wsrc + (size_t)(g * 64 + n) * 64 + q * 8);
    }
    float4 ctg = *(const float4*)(cterm + ((size_t)bx * 64 + n) * 4);
    float c;
    {
        float h0 = hinit[b * 128 + dir * 64 + n];
        c = ftanh(h0);
        hs[n] = f2h(h0);
        int t0 = dir ? (NT - 1) : 0;
        hall[((size_t)b * NT + t0) * NV + n] = h0;
    }
    size_t gbase = (size_t)b * NT * 256;  // [t][64][4]
    int tin0 = dir ? (NT - 1) : 0;
    float4 gc = *(const float4*)(gates + gbase + (size_t)tin0 * 256 + n * 4);
    __syncthreads();
    for (int s = 0; s < NT - 1; s++) {
        WU hh[8];
        const fvec4* hp = (const fvec4*)hs;
        #pragma unroll
        for (int q = 0; q < 8; q++) hh[q].f4 = hp[q];
        float di = 0.f, df = 0.f, dg = 0.f, dq = 0.f;
        #pragma unroll
        for (int q = 0; q < 8; q++) {
            #pragma unroll
            for (int j = 0; j < 4; j++) {
                f16x2 hv2 = hh[q].h[j];
                di = dot2acc(w[0][q].h[j], hv2, di);
                df = dot2acc(w[1][q].h[j], hv2, df);
                dg = dot2acc(w[2][q].h[j], hv2, dg);
                dq = dot2acc(w[3][q].h[j], hv2, dq);
            }
        }
        int tnext = dir ? (NT - 2 - s) : (s + 1);
        float4 gn = *(const float4*)(gates + gbase + (size_t)tnext * 256 + n * 4);
        float ii = fsigm(gc.x + ctg.x + di);
        float ff = fsigm(gc.y + ctg.y + df);
        float gv = ftanh(gc.z + ctg.z + dg);
        float oo = fsigm(gc.w + ctg.w + dq);
        c = ff * c + ii * gv;
        float hv = oo * ftanh(c);
        int tout = dir ? (NT - 2 - s) : (s + 1);
        hall[((size_t)b * NT + tout) * NV + n] = hv;
        __syncthreads();
        hs[n] = f2h(hv);
        __syncthreads();
        gc = gn;
    }
}

// ---------------- K_feat: fused per-feature MLP via bf16 MFMA ----------------
__global__ __launch_bounds__(256) void k_feat(
    const float* __restrict__ xcomp, const unsigned short* __restrict__ wbf,
    const float* __restrict__ wdiag, const float* __restrict__ bfeat,
    const float* __restrict__ Wnl1, const float* __restrict__ bnl1,
    const float* __restrict__ Wnl2, const float* __restrict__ bnl2,
    float* __restrict__ feat_out) {
    int wave = threadIdx.x >> 6; int lane = threadIdx.x & 63;
    int bt0 = blockIdx.x * 64 + wave * 16;
    int r = lane & 15, kc = lane >> 4;
    __shared__ __align__(16) unsigned short hb[4][16 * 32];
    __shared__ __align__(16) float ldsx[4][64 * 16];
    __shared__ __align__(16) float fl[4][16 * 65];
    unsigned short* hbw = hb[wave];
    float* lx = ldsx[wave];
    float* flw = fl[wave];

    short8 a0, a1;
    {
        const float* xr = xcomp + (size_t)(bt0 + r) * NV + kc * 8;
        a0 = pack8(*(const float4*)(xr), *(const float4*)(xr + 4));
        a1 = pack8(*(const float4*)(xr + 32), *(const float4*)(xr + 36));
    }
    {
        int gc0 = kc * 16;
        const float* xr2 = xcomp + (size_t)(bt0 + r) * NV + gc0;
        #pragma unroll
        for (int e = 0; e < 16; e += 4) {
            float4 p = *(const float4*)(xr2 + e);
            lx[(gc0 + e + 0) * 16 + r] = bf2f(f2bf(p.x));
            lx[(gc0 + e + 1) * 16 + r] = bf2f(f2bf(p.y));
            lx[(gc0 + e + 2) * 16 + r] = bf2f(f2bf(p.z));
            lx[(gc0 + e + 3) * 16 + r] = bf2f(f2bf(p.w));
        }
    }
    short8 wb0, wb1;
    {
        const float* w = Wnl1 + r * 32 + kc * 8;
        wb0 = pack8(*(const float4*)w, *(const float4*)(w + 4));
        const float* w2 = Wnl1 + (16 + r) * 32 + kc * 8;
        wb1 = pack8(*(const float4*)w2, *(const float4*)(w2 + 4));
    }
    float w2c0 = Wnl2[r], w2c1 = Wnl2[16 + r];
    float bn0 = bnl1[r], bn1 = bnl1[16 + r];
    float bn2 = bnl2[0];
    __builtin_amdgcn_wave_barrier();

    #pragma unroll 2
    for (int g = 0; g < 64; g++) {
        __builtin_amdgcn_wave_barrier();
        float xv[4];
        #pragma unroll
        for (int i = 0; i < 4; i++) xv[i] = lx[g * 16 + kc * 4 + i];
        float p[4] = {0.f, 0.f, 0.f, 0.f};
        #pragma unroll
        for (int f = 0; f < 2; f++) {
            int n0 = g * 32 + f * 16;
            const unsigned short* wrow = wbf + (size_t)(n0 + r) * 64;
            short8 b0 = *(const short8*)(wrow + kc * 8);
            short8 b1 = *(const short8*)(wrow + 32 + kc * 8);
            f32x4 acc = {0.f, 0.f, 0.f, 0.f};
            acc = __builtin_amdgcn_mfma_f32_16x16x32_bf16(a0, b0, acc, 0, 0, 0);
            acc = __builtin_amdgcn_mfma_f32_16x16x32_bf16(a1, b1, acc, 0, 0, 0);
            int n = n0 + r;
            float wd = wdiag[n], bs = bfeat[n];
            #pragma unroll
            for (int i = 0; i < 4; i++) {
                float h = acc[i] - xv[i] * wd + bs;
                h = fmaxf(h, 0.0f);
                hbw[(kc * 4 + i) * 32 + f * 16 + r] = f2bf(h);
            }
        }
        __builtin_amdgcn_wave_barrier();
        short8 ah = *(const short8*)(hbw + r * 32 + kc * 8);
        f32x4 z0 = {0.f, 0.f, 0.f, 0.f}, z1 = {0.f, 0.f, 0.f, 0.f};
        z0 = __builtin_amdgcn_mfma_f32_16x16x32_bf16(ah, wb0, z0, 0, 0, 0);
        z1 = __builtin_amdgcn_mfma_f32_16x16x32_bf16(ah, wb1, z1, 0, 0, 0);
        #pragma unroll
        for (int i = 0; i < 4; i++) {
            float za = fmaxf(z0[i] + bn0, 0.0f);
            float zb = fmaxf(z1[i] + bn1, 0.0f);
            p[i] = fmaf(za, w2c0, fmaf(zb, w2c1, p[i]));
        }
        #pragma unroll
        for (int m = 1; m < 16; m <<= 1) {
            #pragma unroll
            for (int i = 0; i < 4; i++) p[i] += __shfl_xor(p[i], m, 64);
        }
        if (r == 0) {
            #pragma unroll
            for (int i = 0; i < 4; i++) flw[(kc * 4 + i) * 65 + g] = p[i] + bn2;
        }
    }
    __builtin_amdgcn_wave_barrier();
    #pragma unroll
    for (int q = 0; q < 16; q++)
        feat_out[(size_t)(bt0 + q) * NV + lane] = flw[q * 65 + lane];
}

// ---------------- K_post: fused rnn_imp GEMM + beta GEMM + fusion + scaling ----------------
// out0 holds hf_all (in), out1 holds hb_all (in), out2 holds feat (in).
// Writes out0=rnn*mm+mn, out1=feat*mm+mn, out2=final*mm+mn.
__global__ __launch_bounds__(256) void k_post(
    const float* __restrict__ gam, const float* __restrict__ masks,
    const unsigned short* __restrict__ wri_bf, const unsigned short* __restrict__ wfu_bf,
    const float* __restrict__ bri, const float* __restrict__ bfu,
    const float* __restrict__ mmn_ws, const float* __restrict__ minv,
    float* out0, float* out1, float* out2) {
    int wave = threadIdx.x >> 6, lane = threadIdx.x & 63;
    int bt0 = blockIdx.x * 64 + wave * 16;
    int r = lane & 15, kc = lane >> 4;
    int b = bt0 >> 8;
    const float* h0r = out0 + (size_t)(bt0 + r) * NV + kc * 8;
    const float* h1r = out1 + (size_t)(bt0 + r) * NV + kc * 8;
    const float* gr  = gam  + (size_t)(bt0 + r) * NV + kc * 8;
    const float* mr  = masks + (size_t)(bt0 + r) * NV + kc * 8;
    short8 A0 = pack8(*(const float4*)(h0r), *(const float4*)(h0r + 4));
    short8 A1 = pack8(*(const float4*)(h0r + 32), *(const float4*)(h0r + 36));
    short8 A2 = pack8(*(const float4*)(h1r), *(const float4*)(h1r + 4));
    short8 A3 = pack8(*(const float4*)(h1r + 32), *(const float4*)(h1r + 36));
    short8 G0 = pack8(*(const float4*)(gr), *(const float4*)(gr + 4));
    short8 G1 = pack8(*(const float4*)(gr + 32), *(const float4*)(gr + 36));
    short8 M0 = pack8(*(const float4*)(mr), *(const float4*)(mr + 4));
    short8 M1 = pack8(*(const float4*)(mr + 32), *(const float4*)(mr + 36));
    #pragma unroll
    for (int nt = 0; nt < 4; nt++) {
        int n = nt * 16 + r;
        const unsigned short* wr = wri_bf + (size_t)n * 128 + kc * 8;
        const unsigned short* wf = wfu_bf + (size_t)n * 128 + kc * 8;
        float bi = bri[n], bf_ = bfu[n];
        f32x4 racc = {bi, bi, bi, bi};
        f32x4 bacc = {bf_, bf_, bf_, bf_};
        racc = __builtin_amdgcn_mfma_f32_16x16x32_bf16(A0, *(const short8*)(wr), racc, 0, 0, 0);
        racc = __builtin_amdgcn_mfma_f32_16x16x32_bf16(A1, *(const short8*)(wr + 32), racc, 0, 0, 0);
        racc = __builtin_amdgcn_mfma_f32_16x16x32_bf16(A2, *(const short8*)(wr + 64), racc, 0, 0, 0);
        racc = __builtin_amdgcn_mfma_f32_16x16x32_bf16(A3, *(const short8*)(wr + 96), racc, 0, 0, 0);
        bacc = __builtin_amdgcn_mfma_f32_16x16x32_bf16(G0, *(const short8*)(wf), bacc, 0, 0, 0);
        bacc = __builtin_amdgcn_mfma_f32_16x16x32_bf16(G1, *(const short8*)(wf + 32), bacc, 0, 0, 0);
        bacc = __builtin_amdgcn_mfma_f32_16x16x32_bf16(M0, *(const short8*)(wf + 64), bacc, 0, 0, 0);
        bacc = __builtin_amdgcn_mfma_f32_16x16x32_bf16(M1, *(const short8*)(wf + 96), bacc, 0, 0, 0);
        float mm = mmn_ws[b * NV + n], mn = minv[b * NV + n];
        #pragma unroll
        for (int i = 0; i < 4; i++) {
            int row = bt0 + kc * 4 + i;
            size_t idx = (size_t)row * NV + n;
            float rn = racc[i];
            float beta = fsigm(bacc[i]);
            float ft = out2[idx];
            float fin = beta * ft + (1.0f - beta) * rn;
            out0[idx] = fmaf(rn, mm, mn);
            out1[idx] = fmaf(ft, mm, mn);
            out2[idx] = fmaf(fin, mm, mn);
        }
    }
}

extern "C" void kernel_launch(void* const* d_in, const int* in_sizes, int n_in,
                              void* d_out, int out_size, void* d_ws, size_t ws_size,
                              hipStream_t stream) {
    const int*   lengths  = (const int*)d_in[0];
    const float* values   = (const float*)d_in[1];
    const float* masks    = (const float*)d_in[2];
    const float* deltas   = (const float*)d_in[3];
    const float* min_vals = (const float*)d_in[4];
    const float* max_vals = (const float*)d_in[5];
    const float* W_decay  = (const float*)d_in[6];
    const float* b_decay  = (const float*)d_in[7];
    const float* W_feat   = (const float*)d_in[8];
    const float* b_feat   = (const float*)d_in[9];
    const float* W_nl1    = (const float*)d_in[10];
    const float* b_nl1    = (const float*)d_in[11];
    const float* W_nl2    = (const float*)d_in[12];
    const float* b_nl2    = (const float*)d_in[13];
    const float* Wc1      = (const float*)d_in[14];
    const float* bc1      = (const float*)d_in[15];
    const float* Wc2      = (const float*)d_in[16];
    const float* bc2      = (const float*)d_in[17];
    const float* W_ih_g   = (const float*)d_in[18];
    const float* W_hh_g   = (const float*)d_in[19];
    const float* b_ih_g   = (const float*)d_in[20];
    const float* b_hh_g   = (const float*)d_in[21];
    const float* W_init   = (const float*)d_in[22];
    const float* b_init   = (const float*)d_in[23];
    const float* W_ih_f   = (const float*)d_in[24];
    const float* W_hh_f   = (const float*)d_in[25];
    const float* b_ih_f   = (const float*)d_in[26];
    const float* b_hh_f   = (const float*)d_in[27];
    const float* W_ih_b   = (const float*)d_in[28];
    const float* W_hh_b   = (const float*)d_in[29];
    const float* b_ih_b   = (const float*)d_in[30];
    const float* b_hh_b   = (const float*)d_in[31];
    const float* W_ri     = (const float*)d_in[32];
    const float* b_ri     = (const float*)d_in[33];
    const float* W_fu     = (const float*)d_in[34];
    const float* b_fu     = (const float*)d_in[35];

    float* ws = (float*)d_ws;
    float* xcomp  = ws;                     // 2097152
    float* gam    = ws + 2097152;           // 2097152
    unsigned short* wri_bf = (unsigned short*)(ws + 4194304); // 8192 u16
    unsigned short* wfu_bf = (unsigned short*)(ws + 4198400); // 8192 u16
    float* stats  = ws + 6291456;           // 32768
    float* mmn    = ws + 6324224;           // 8192
    float* nmeans = ws + 6332416;           // 8192
    float* ctx    = ws + 6340608;           // 8192
    float* hinit  = ws + 6348800;           // 16384
    unsigned short* wbf = (unsigned short*)(ws + 6365184);  // 131072 u16
    float* wdiag  = ws + 6430720;           // 2048
    unsigned short* wgf = (unsigned short*)(ws + 6432768);  // 32768 u16
    unsigned short* wgb = (unsigned short*)(ws + 6449152);  // 32768 u16
    unsigned short* wgg = (unsigned short*)(ws + 6465536);  // 12288 u16
    unsigned short* whhf_h = (unsigned short*)(ws + 6471680); // 16384 u16
    unsigned short* whhb_h = (unsigned short*)(ws + 6479872); // 16384 u16
    unsigned short* whhg_h = (unsigned short*)(ws + 6488064); // 3072 u16
    float* cterm  = ws + 6489600;           // 65536
    float* gates_f = ws + 6555136;          // 8388608
    float* gates_b = ws + 14943744;         // 8388608
    float* gates_g = ws + 23332352;         // 3145728  (end ≈ 106 MB)

    float* out0 = (float*)d_out;
    float* out1 = out0 + NBTV;
    float* out2 = out0 + 2 * NBTV;

    k_conv<<<512, 256, 0, stream>>>(W_feat, W_ih_f, W_ih_b, W_ih_g, W_hh_f, W_hh_b, W_hh_g,
                                    W_ri, W_fu,
                                    wbf, wdiag, wgf, wgb, wgg, whhf_h, whhb_h, whhg_h,
                                    wri_bf, wfu_bf);
    k_stats<<<NB, 256, 0, stream>>>(lengths, values, masks, min_vals, max_vals, stats, mmn, nmeans);
    k_fill<<<NB, 256, 0, stream>>>(values, masks, deltas, min_vals, W_decay, b_decay, mmn, nmeans, xcomp, gam);
    k_gates<<<NBT / 64, 256, 0, stream>>>(xcomp, masks, wgf, wgb, wgg, b_ih_g, gates_f, gates_b, gates_g);
    k_feat<<<NBT / 64, 256, 0, stream>>>(xcomp, wbf, wdiag, b_feat, W_nl1, b_nl1, W_nl2, b_nl2, out2);
    k_ctxmlp<<<NB, 64, 0, stream>>>(stats, Wc1, bc1, Wc2, bc2, ctx);
    k_gru<<<64, 64, 0, stream>>>(gates_g, lengths, whhg_h, b_hh_g, ctx);
    k_hinit<<<NB, 128, 0, stream>>>(ctx, W_init, b_init, hinit);
    k_cterm<<<256, 256, 0, stream>>>(ctx, W_ih_f, W_ih_b, b_ih_f, b_hh_f, b_ih_b, b_hh_b, cterm);
    k_lstm<<<256, 64, 0, stream>>>(gates_f, gates_b, cterm, hinit, whhf_h, whhb_h, out0, out1);
    k_post<<<NBT / 64, 256, 0, stream>>>(gam, masks, wri_bf, wfu_bf, b_ri, b_fu, mmn, min_vals,
                                         out0, out1, out2);
}